// Round 9
// baseline (790.369 us; speedup 1.0000x reference)
//
#include <hip/hip_runtime.h>
#include <stdint.h>

// ---------------------------------------------------------------------------
// B=256, H=W=14, HW=196, TS=0.03, TC=0.07, TP_K=19, TN_K=98
// Conv inputs: padded 16x16 cell grid per image (1-cell zero halo):
// cell = b*256 + (h+1)*16 + (w+1). Conv 3x3 = 9 cell-row shifts d=dh*16+dw.
// convtap6_k: block = ONE image (M padded 196->224 rows) x 128 N. The A
// window per kc is EXACTLY the image's 256 cell rows (36.9 KB) — covers all
// 9 taps incl. halo. acc 7x4/wave. M-tiling: each 16x16 MFMA tile = a 2x8
// PIXEL BLOCK (tq -> dh=tq>>3, dw=tq&7; mi -> h-pair; wm -> w-half): A-read
// bank residue uniform (the pinned 1.652e7 SQ_LDS_BANK_CONFLICT = 4.13e6
// b128 reads x 4 = intrinsic 2-way wave64 aliasing, free per m136 — benign).
// B PATH (R8-measured, kept): weights in per-wave REGISTERS, fragment-packed;
// b0 dbuf one step ahead; b1 loaded at step top, used after h0 cluster;
// af0+af1 before h0 cluster; 9-tap loop fully unrolled (A tap offsets are
// ds_read immediates; no div/mod); s_setprio around MFMA clusters.
// R8 result: conv2 204us, MfmaUtil 61%, VALUBusy 19.6%.
// R9 CHANGE — LDS A DOUBLE-BUFFER (2x36.9KB = 73.7KB, still 2 blocks/CU):
// stageA(kc+1) into buf^1 issued at tap t=0 of kc -> streams in under ~9
// taps of MFMA. ONE barrier per kc (its implicit per-wave vmcnt(0) is cheap:
// the prefetch is ~30K cyc old). Removes the kc-boundary barrier-drain
// (sync -> 36.9KB HBM fetch -> sync with zero covering work, 7x/5x per
// dispatch ~= 8-10% of conv time — the m97 disease at kc granularity).
// Block mapping: DEFAULT (img=bx, n0=by*128): same-img blocks on same XCD.
// Grid 256x4 at 2 blocks/CU -> exactly 4 slots/CU, no tail quantization.
// NOTE: workspace regions are reused; size each by the MAX of its occupants.
// ---------------------------------------------------------------------------

typedef __attribute__((ext_vector_type(8))) short bf16x8;
typedef __attribute__((ext_vector_type(4))) float f32x4;

__device__ __forceinline__ unsigned short f2bf(float x) {
  unsigned u = __float_as_uint(x);
  unsigned r = u + 0x7FFFu + ((u >> 16) & 1u);  // RNE, no NaNs here
  return (unsigned short)(r >> 16);
}
__device__ __forceinline__ float bf2f(unsigned short h) {
  return __uint_as_float(((unsigned)h) << 16);
}

typedef const __attribute__((address_space(1))) void* gptr1_t;
typedef __attribute__((address_space(3))) void* lptr3_t;
__device__ __forceinline__ void gload_lds16(const void* g, void* l) {
  __builtin_amdgcn_global_load_lds((gptr1_t)g, (lptr3_t)l, 16, 0, 0);
}

__device__ __forceinline__ float waveSum(float v) {
#pragma unroll
  for (int m = 1; m < 64; m <<= 1) v += __shfl_xor(v, m, 64);
  return v;
}
__device__ __forceinline__ float waveMax(float v) {
#pragma unroll
  for (int m = 1; m < 64; m <<= 1) v = fmaxf(v, __shfl_xor(v, m, 64));
  return v;
}
template <int NW>
__device__ __forceinline__ float blockSum(float v) {
  __shared__ float sh[NW];
  v = waveSum(v);
  int wv = threadIdx.x >> 6, ln = threadIdx.x & 63;
  if (ln == 0) sh[wv] = v;
  __syncthreads();
  float r = 0.f;
#pragma unroll
  for (int w = 0; w < NW; ++w) r += sh[w];
  __syncthreads();
  return r;
}
template <int NW>
__device__ __forceinline__ float blockMax(float v) {
  __shared__ float sh[NW];
  v = waveMax(v);
  int wv = threadIdx.x >> 6, ln = threadIdx.x & 63;
  if (ln == 0) sh[wv] = v;
  __syncthreads();
  float r = -3.4e38f;
#pragma unroll
  for (int w = 0; w < NW; ++w) r = fmaxf(r, sh[w]);
  __syncthreads();
  return r;
}

#define RA 65536  // rows per k-slice of conv input buffers

// ---------------------------------------------------------------------------
// convtap6_k: one image per block-x. C[p,n] = sum_t sum_k A[cell(p)+d_t,k]B[t,n,k]
// 256 thr, 4 waves (wm in {0,1}: w-half, wn in {0,1}: 64 cols), acc 7x4 of
// 16x16x32 bf16 MFMA. A: [kc][RA][72] shorts; LDS window DOUBLE-BUFFERED
// 2x256x72 (73.7 KB). B: fragment-packed [t][kc][g][h][lane][8], reg-loaded.
// EPI 0: relu -> x1b (cell rows, k-major slices). EPI 1: bf16 -> fv compact.
// ---------------------------------------------------------------------------
template <int KC, int EPI>
__global__ __launch_bounds__(256, 2) void convtap6_k(
    const unsigned short* __restrict__ A, const unsigned short* __restrict__ Bw,
    unsigned short* __restrict__ C) {
  __shared__ __align__(16) short Ah[2 * 256 * 72];
  const int tid = threadIdx.x;
  const int wave = tid >> 6, lane = tid & 63;
  const int wm = wave >> 1, wn = wave & 1;
  const int quad = lane >> 4, tq = lane & 15;
  const int img = blockIdx.x, n0 = blockIdx.y * 128;

  // A BYTE-base per mi, biased -17 rows so every tap offset immediate >= 0:
  // read addr = base + pab[mi] + OFF(t,h), OFF = (17+(dh-1)*16+(dw-1))*144+h*64
  int pab[7];
  {
    const int dh = tq >> 3;
    int wq = wm * 8 + (tq & 7);          // w' in 0..15
    if (wq == 0) wq = 8;                 // dead col -> mirrored valid col
    else if (wq == 15) wq = 7;
#pragma unroll
    for (int mi = 0; mi < 7; ++mi) {
      int pr = (1 + 2 * mi + dh) * 16 + wq;   // 17..239
      pab[mi] = (pr - 17) * 144 + quad * 16;  // bytes
    }
  }
  // B fragment base (shorts): (t*KC+kc)*32768 + g*1024 + h*512 + lane*8
  const int gb = (n0 >> 4) + wn * 4;

  const char* Ab = (const char*)A;
  const int l16 = lane * 16;

  f32x4 acc[7][4];
#pragma unroll
  for (int mi = 0; mi < 7; ++mi)
#pragma unroll
    for (int ni = 0; ni < 4; ++ni) {
      f32x4 z = {0.f, 0.f, 0.f, 0.f};
      acc[mi][ni] = z;
    }

  auto stageA = [&](int kc, int buf) {
    size_t s0 = ((size_t)kc * RA + img * 256) * 144;
    char* dst = (char*)Ah + buf * (256 * 144);
#pragma unroll
    for (int i = 0; i < 9; ++i) {
      int c = wave + i * 4;  // 36 chunks of 1024 B
      gload_lds16(Ab + s0 + (size_t)c * 1024 + l16, dst + c * 1024);
    }
  };

  stageA(0, 0);
  bf16x8 b0[4], b1[4];
  {  // h0 frags of (kc=0,t=0): overlaps A staging + barrier
    const size_t w0 = ((size_t)gb * 128 + lane) * 8;
#pragma unroll
    for (int ni = 0; ni < 4; ++ni)
      b0[ni] = *(const bf16x8*)&Bw[w0 + (size_t)ni * 1024];
  }
  __syncthreads();

#pragma unroll 1
  for (int kc = 0; kc < KC; ++kc) {
    const size_t bk = ((size_t)kc * 4096 + gb * 128 + lane) * 8;  // shorts
    const char* AhB = (const char*)Ah + (kc & 1) * (256 * 144);
#pragma unroll
    for (int t = 0; t < 9; ++t) {
      const size_t tof = (size_t)t * KC * 32768;  // compile-time
      // async prefetch of next kc's A window into the other buffer:
      // issued at t=0, streams in under the remaining ~8 taps of MFMA.
      if (t == 0 && kc + 1 < KC) stageA(kc + 1, (kc & 1) ^ 1);
      // h1 frags of this step: used after the h0 cluster (~650 cyc)
#pragma unroll
      for (int ni = 0; ni < 4; ++ni)
        b1[ni] = *(const bf16x8*)&Bw[bk + tof + (size_t)ni * 1024 + 512];
      // prefetch next step's h0 frags (~full step of cover)
      bf16x8 b0n[4];
      const bool last = (t == 8) && (kc == KC - 1);
      if (!last) {
        const size_t nbase =
            (t < 8) ? bk + (size_t)(t + 1) * KC * 32768 : bk + 32768;
#pragma unroll
        for (int ni = 0; ni < 4; ++ni)
          b0n[ni] = *(const bf16x8*)&Bw[nbase + (size_t)ni * 1024];
      }
      // A fragments: base reg + CONSTANT offset (folds into ds_read imm)
      const int OFF = (17 + (t / 3 - 1) * 16 + (t % 3 - 1)) * 144;
      bf16x8 af0[7], af1[7];
#pragma unroll
      for (int mi = 0; mi < 7; ++mi)
        af0[mi] = *(const bf16x8*)(AhB + pab[mi] + OFF);
#pragma unroll
      for (int mi = 0; mi < 7; ++mi)
        af1[mi] = *(const bf16x8*)(AhB + pab[mi] + OFF + 64);
      __builtin_amdgcn_s_setprio(1);
#pragma unroll
      for (int mi = 0; mi < 7; ++mi)
#pragma unroll
        for (int ni = 0; ni < 4; ++ni)
          acc[mi][ni] = __builtin_amdgcn_mfma_f32_16x16x32_bf16(
              af0[mi], b0[ni], acc[mi][ni], 0, 0, 0);
#pragma unroll
      for (int mi = 0; mi < 7; ++mi)
#pragma unroll
        for (int ni = 0; ni < 4; ++ni)
          acc[mi][ni] = __builtin_amdgcn_mfma_f32_16x16x32_bf16(
              af1[mi], b1[ni], acc[mi][ni], 0, 0, 0);
      __builtin_amdgcn_s_setprio(0);
      if (!last) {
#pragma unroll
        for (int ni = 0; ni < 4; ++ni) b0[ni] = b0n[ni];  // SSA rename, free
      }
    }
    // single barrier per kc: all waves issued their buf^1 writes above;
    // per-wave vmcnt(0) at barrier entry is cheap (prefetch ~9 taps old).
    if (kc + 1 < KC) __syncthreads();
  }

#pragma unroll
  for (int mi = 0; mi < 7; ++mi) {
#pragma unroll
    for (int r = 0; r < 4; ++r) {
      int idx = quad * 4 + r;            // M-row within tile, 0..15
      int wv = wm * 8 + (idx & 7);       // w' in 0..15
      if (wv == 0 || wv == 15) continue;  // dead column (halo)
      int hh = 1 + 2 * mi + (idx >> 3);  // h' in 1..14
      if (EPI == 0) {
        int cell = img * 256 + hh * 16 + wv;
        int slice = (n0 >> 6) + wn;
        size_t ob = ((size_t)slice * RA + cell) * 72 + tq;
#pragma unroll
        for (int ni = 0; ni < 4; ++ni)
          C[ob + ni * 16] = f2bf(fmaxf(acc[mi][ni][r], 0.f));
      } else {
        int p = (hh - 1) * 14 + (wv - 1);
        size_t ob = (size_t)(img * 196 + p) * 512 + n0 + wn * 64 + tq;
#pragma unroll
        for (int ni = 0; ni < 4; ++ni)
          C[ob + ni * 16] = f2bf(acc[mi][ni][r]);
      }
    }
  }
}

// ---------------------------------------------------------------------------
// gemm1_k: C[m,n] = sum_k A[m,k]*B[n,k]; 128x128 tile, 4 waves, BK=64,
// XOR-swizzled LDS. EPI: 0 relu->bf16, 2 f32, 3 f32 * rs[m] (row scale).
// ---------------------------------------------------------------------------
template <int K, int NLD, int EPI>
__global__ __launch_bounds__(256, 2) void gemm1_k(
    const unsigned short* __restrict__ A, const unsigned short* __restrict__ Bw,
    void* __restrict__ C, const float* __restrict__ rs) {
  __shared__ short As[128 * 64];
  __shared__ short Bs[128 * 64];
  const int tid = threadIdx.x;
  const int wave = tid >> 6, lane = tid & 63;
  const int m0 = blockIdx.x * 128, n0 = blockIdx.y * 128;
  const int rr8 = lane >> 3, seg = lane & 7, gseg = seg ^ rr8;
  const int wm = wave >> 1, wn = wave & 1;
  const int quad = lane >> 4, tq = lane & 15;

  size_t asrc[4], bsrc[4];
#pragma unroll
  for (int i8 = 0; i8 < 4; ++i8) {
    int rloc = wave * 32 + i8 * 8 + rr8;
    asrc[i8] = (size_t)(m0 + rloc) * K + gseg * 8;
    bsrc[i8] = (size_t)(n0 + rloc) * K + gseg * 8;
  }

  f32x4 acc[4][4];
#pragma unroll
  for (int mi = 0; mi < 4; ++mi)
#pragma unroll
    for (int ni = 0; ni < 4; ++ni) {
      f32x4 z = {0.f, 0.f, 0.f, 0.f};
      acc[mi][ni] = z;
    }

#pragma unroll 1
  for (int kc2 = 0; kc2 < K / 64; ++kc2) {
    int kb = kc2 * 64;
    __syncthreads();
#pragma unroll
    for (int i8 = 0; i8 < 4; ++i8) {
      gload_lds16(A + asrc[i8] + kb, &As[(wave * 32 + i8 * 8) * 64]);
      gload_lds16(Bw + bsrc[i8] + kb, &Bs[(wave * 32 + i8 * 8) * 64]);
    }
    __syncthreads();
#pragma unroll
    for (int h = 0; h < 2; ++h) {
      bf16x8 af[4], bfr[4];
#pragma unroll
      for (int mi = 0; mi < 4; ++mi) {
        int row = wm * 64 + mi * 16 + tq;
        af[mi] = *(const bf16x8*)&As[row * 64 +
                                     ((((h << 2) | quad) ^ (row & 7)) << 3)];
      }
#pragma unroll
      for (int ni = 0; ni < 4; ++ni) {
        int row = wn * 64 + ni * 16 + tq;
        bfr[ni] = *(const bf16x8*)&Bs[row * 64 +
                                      ((((h << 2) | quad) ^ (row & 7)) << 3)];
      }
#pragma unroll
      for (int mi = 0; mi < 4; ++mi)
#pragma unroll
        for (int ni = 0; ni < 4; ++ni)
          acc[mi][ni] = __builtin_amdgcn_mfma_f32_16x16x32_bf16(
              af[mi], bfr[ni], acc[mi][ni], 0, 0, 0);
    }
  }

#pragma unroll
  for (int mi = 0; mi < 4; ++mi) {
#pragma unroll
    for (int r = 0; r < 4; ++r) {
      int m = m0 + wm * 64 + mi * 16 + quad * 4 + r;
      float sc = (EPI == 3) ? rs[m] : 1.f;
      size_t obase = (size_t)m * NLD + n0 + wn * 64 + tq;
#pragma unroll
      for (int ni = 0; ni < 4; ++ni) {
        float v = acc[mi][ni][r];
        size_t idx = obase + ni * 16;
        if (EPI == 0)
          ((unsigned short*)C)[idx] = f2bf(fmaxf(v, 0.f));
        else if (EPI == 2)
          ((float*)C)[idx] = v;
        else
          ((float*)C)[idx] = v * sc;
      }
    }
  }
}

// Xm = (iv+eps).fa^T and Vm = indn.indn^T in one dispatch (blockIdx.z picks)
__global__ __launch_bounds__(256, 2) void gemm_xv_k(
    const unsigned short* __restrict__ ivpb, const unsigned short* __restrict__ fab,
    const unsigned short* __restrict__ indnb, float* __restrict__ Xm,
    float* __restrict__ Vm) {
  const unsigned short* A = blockIdx.z ? indnb : ivpb;
  const unsigned short* Bw = blockIdx.z ? indnb : fab;
  float* C = blockIdx.z ? Vm : Xm;
  __shared__ short As[128 * 64];
  __shared__ short Bs[128 * 64];
  const int tid = threadIdx.x;
  const int wave = tid >> 6, lane = tid & 63;
  const int m0 = blockIdx.x * 128, n0 = blockIdx.y * 128;
  const int rr8 = lane >> 3, seg = lane & 7, gseg = seg ^ rr8;
  const int wm = wave >> 1, wn = wave & 1;
  const int quad = lane >> 4, tq = lane & 15;
  size_t asrc[4], bsrc[4];
#pragma unroll
  for (int i8 = 0; i8 < 4; ++i8) {
    int rloc = wave * 32 + i8 * 8 + rr8;
    asrc[i8] = (size_t)(m0 + rloc) * 512 + gseg * 8;
    bsrc[i8] = (size_t)(n0 + rloc) * 512 + gseg * 8;
  }
  f32x4 acc[4][4];
#pragma unroll
  for (int mi = 0; mi < 4; ++mi)
#pragma unroll
    for (int ni = 0; ni < 4; ++ni) {
      f32x4 z = {0.f, 0.f, 0.f, 0.f};
      acc[mi][ni] = z;
    }
#pragma unroll 1
  for (int kc2 = 0; kc2 < 8; ++kc2) {
    int kb = kc2 * 64;
    __syncthreads();
#pragma unroll
    for (int i8 = 0; i8 < 4; ++i8) {
      gload_lds16(A + asrc[i8] + kb, &As[(wave * 32 + i8 * 8) * 64]);
      gload_lds16(Bw + bsrc[i8] + kb, &Bs[(wave * 32 + i8 * 8) * 64]);
    }
    __syncthreads();
#pragma unroll
    for (int h = 0; h < 2; ++h) {
      bf16x8 af[4], bfr[4];
#pragma unroll
      for (int mi = 0; mi < 4; ++mi) {
        int row = wm * 64 + mi * 16 + tq;
        af[mi] = *(const bf16x8*)&As[row * 64 +
                                     ((((h << 2) | quad) ^ (row & 7)) << 3)];
      }
#pragma unroll
      for (int ni = 0; ni < 4; ++ni) {
        int row = wn * 64 + ni * 16 + tq;
        bfr[ni] = *(const bf16x8*)&Bs[row * 64 +
                                      ((((h << 2) | quad) ^ (row & 7)) << 3)];
      }
#pragma unroll
      for (int mi = 0; mi < 4; ++mi)
#pragma unroll
        for (int ni = 0; ni < 4; ++ni)
          acc[mi][ni] = __builtin_amdgcn_mfma_f32_16x16x32_bf16(
              af[mi], bfr[ni], acc[mi][ni], 0, 0, 0);
    }
  }
#pragma unroll
  for (int mi = 0; mi < 4; ++mi)
#pragma unroll
    for (int r = 0; r < 4; ++r) {
      int m = m0 + wm * 64 + mi * 16 + quad * 4 + r;
      size_t obase = (size_t)m * 256 + n0 + wn * 64 + tq;
#pragma unroll
      for (int ni = 0; ni < 4; ++ni) C[obase + ni * 16] = acc[mi][ni][r];
    }
}

// --------------------------- prep (fused) ----------------------------------
// ranges: ea/Wf1/Wf2 casts | wb1 build | wb2 build | x1b halo zeroing
// wb layout (fragment-packed): flat index j =
//   (((t*KC+kc)*32 + g)*2 + h)*512 + quad*128 + tq*8 + jj
// value = Wc[n = g*16+tq][cin = kc*64 + h*32 + quad*8 + jj][tap t]
// -> writes are perfectly linear; the conv kernel reads 1KB coalesced spans.
__global__ void prep_all_k(const float* __restrict__ ea,
                           const float* __restrict__ Wf1,
                           const float* __restrict__ Wf2,
                           const float* __restrict__ Wc1,
                           const float* __restrict__ Wc2,
                           unsigned short* __restrict__ eab,
                           unsigned short* __restrict__ wf1b,
                           unsigned short* __restrict__ wf2b,
                           unsigned short* __restrict__ wb1,
                           unsigned short* __restrict__ wb2,
                           unsigned int* __restrict__ x1u) {
  int i = blockIdx.x * 256 + threadIdx.x;
  if (i < 524288) {
    eab[i] = f2bf(ea[i]);
  } else if (i < 1572864) {
    int j = i - 524288;
    wf1b[j] = f2bf(Wf1[j]);
  } else if (i < 1835008) {
    int j = i - 1572864;
    wf2b[j] = f2bf(Wf2[j]);
  } else if (i < 3604480) {
    int j = i - 1835008;  // wb1: 9*6*32768 fragment-packed <- Wc1[n][384][3][3]
    int t = j / (6 * 32768), r = j - t * (6 * 32768);
    int kc = r / 32768, r2 = r - kc * 32768;
    int g = r2 >> 10, h = (r2 >> 9) & 1, quad = (r2 >> 7) & 3;
    int tq = (r2 >> 3) & 15, jj = r2 & 7;
    int n = g * 16 + tq, cin = kc * 64 + h * 32 + quad * 8 + jj;
    wb1[j] = f2bf(Wc1[(n * 384 + cin) * 9 + t]);
  } else if (i < 5963776) {
    int j = i - 3604480;  // wb2: 9*8*32768 fragment-packed <- Wc2[n][512][3][3]
    int t = j / (8 * 32768), r = j - t * (8 * 32768);
    int kc = r / 32768, r2 = r - kc * 32768;
    int g = r2 >> 10, h = (r2 >> 9) & 1, quad = (r2 >> 7) & 3;
    int tq = (r2 >> 3) & 15, jj = r2 & 7;
    int n = g * 16 + tq, cin = kc * 64 + h * 32 + quad * 8 + jj;
    wb2[j] = f2bf(Wc2[(n * 512 + cin) * 9 + t]);
  } else {
    int j = i - 5963776;  // 15360 halo rows x 8 slices x 32 uints
    int hr = j >> 8, u = j & 255;
    int slice = u >> 5, uu = u & 31;
    int b = hr / 60, c = hr - b * 60;
    int cell;
    if (c < 16) cell = c;
    else if (c < 32) cell = 240 + (c - 16);
    else if (c < 46) cell = (c - 31) * 16;
    else cell = (c - 45) * 16 + 15;
    x1u[((size_t)slice * RA + b * 256 + cell) * 36 + uu] = 0u;
  }
}

// ev (256,384,14,14) fp32 -> evb [kc6][RA][72] bf16 (halo cells zero)
__global__ __launch_bounds__(256) void evpad_k(const float* __restrict__ ev,
                                               unsigned short* __restrict__ out) {
  int b = blockIdx.x, ct = blockIdx.y;  // channel tile: c0 = ct*64
  __shared__ float tile[64][197];
  int tid = threadIdx.x;
  const float* src = ev + ((size_t)b * 384 + ct * 64) * 196;
#pragma unroll 1
  for (int it = 0; it < 49; ++it) {
    int idx = it * 256 + tid;
    int c = idx / 196, p = idx - c * 196;
    tile[c][p] = src[idx];
  }
  __syncthreads();
  unsigned short* dst = out + ((size_t)ct * RA + b * 256) * 72;
#pragma unroll 1
  for (int it = 0; it < 64; ++it) {
    int idx = it * 256 + tid;
    int cell = idx >> 6, c = idx & 63;
    int h = (cell >> 4) - 1, w = (cell & 15) - 1;
    float v = ((unsigned)h < 14u && (unsigned)w < 14u) ? tile[c][h * 14 + w]
                                                       : 0.f;
    dst[(size_t)cell * 72 + c] = f2bf(v);
  }
}

// --------------------------- pooling / norms -------------------------------

// fused: masked mean pool + per-pixel inverse norm (rn) + ind normalization
__global__ __launch_bounds__(512) void pool_k(
    const unsigned short* __restrict__ fv, const int* __restrict__ masks,
    unsigned short* __restrict__ indnb, unsigned short* __restrict__ ivpb,
    float* __restrict__ Pi, float* __restrict__ rn) {
  int b = blockIdx.x;
  int w = threadIdx.x >> 6, lane = threadIdx.x & 63;
  __shared__ float red[8][512];
  __shared__ float msh[8];
  float acc[8] = {0.f, 0.f, 0.f, 0.f, 0.f, 0.f, 0.f, 0.f};
  float msum = 0.f;
  for (int p = w; p < 196; p += 8) {
    float m = (float)masks[b * 196 + p];
    msum += m;
    uint4 d = *(const uint4*)(fv + (size_t)(b * 196 + p) * 512 + lane * 8);
    const unsigned short* hp = (const unsigned short*)&d;
    float ss = 0.f;
#pragma unroll
    for (int k = 0; k < 8; ++k) {
      float x = bf2f(hp[k]);
      ss += x * x;
      acc[k] += m * x;
    }
    ss = waveSum(ss);
    if (lane == 0) rn[b * 196 + p] = 1.f / fmaxf(sqrtf(ss), 1e-12f);
  }
#pragma unroll
  for (int k = 0; k < 8; ++k) red[w][lane * 8 + k] = acc[k];
  if (lane == 0) msh[w] = msum;
  __syncthreads();
  int tid = threadIdx.x;
  float s = 0.f, mtot = 0.f;
#pragma unroll
  for (int ww = 0; ww < 8; ++ww) {
    s += red[ww][tid];
    mtot += msh[ww];
  }
  float v = s / mtot;  // indv[b, tid]
  float ss2 = blockSum<8>(v * v);
  float sc = 1.f / fmaxf(sqrtf(ss2), 1e-12f);
  indnb[b * 512 + tid] = f2bf(v * sc);
  float ve = v + 1e-6f;
  ivpb[b * 512 + tid] = f2bf(ve);
  float p2 = blockSum<8>(ve * ve);
  if (tid == 0) Pi[b] = p2;
}

// fa fp32 -> bf16 + Qj = ||fa_j||^2
__global__ __launch_bounds__(512) void fanorm_k(const float* __restrict__ fa,
                                                unsigned short* __restrict__ fab,
                                                float* __restrict__ Qj) {
  int b = blockIdx.x, tid = threadIdx.x;
  float v = fa[b * 512 + tid];
  fab[b * 512 + tid] = f2bf(v);
  float q = blockSum<8>(v * v);
  if (tid == 0) Qj[b] = q;
}

// ------------------------------ SP / SN ------------------------------------

__device__ __forceinline__ float radix_kth(unsigned k0, unsigned k1, unsigned k2,
                                           unsigned k3, int k) {
  unsigned prefix = 0;
  int kk = k;
#pragma unroll 1
  for (int bit = 31; bit >= 14; --bit) {  // 18 steps; thr err ~2^-9 rel, ok
    unsigned thi = (prefix >> bit) | 1u;
    int c = __popcll(__ballot((k0 >> bit) == thi)) +
            __popcll(__ballot((k1 >> bit) == thi)) +
            __popcll(__ballot((k2 >> bit) == thi)) +
            __popcll(__ballot((k3 >> bit) == thi));
    if (kk <= c)
      prefix |= (1u << bit);
    else
      kk -= c;
  }
  unsigned u = (prefix & 0x80000000u) ? (prefix ^ 0x80000000u) : ~prefix;
  return __uint_as_float(u);
}
__device__ __forceinline__ unsigned sortkey(float x) {
  unsigned u = __float_as_uint(x);
  return u ^ (((int)u >> 31) | 0x80000000u);
}

__global__ __launch_bounds__(256) void spsn_k(const float* __restrict__ Sij,
                                              float* __restrict__ SP,
                                              float* __restrict__ SN) {
  int i = blockIdx.x, jg = blockIdx.y;
  int tid = threadIdx.x, wave = tid >> 6, lane = tid & 63;
  __shared__ float tile[196 * 65];
#pragma unroll 1
  for (int it = 0; it < 49; ++it) {
    int lin = it * 256 + tid;
    int p = lin >> 6, j = lin & 63;
    tile[p * 65 + j] = Sij[(size_t)(i * 196 + p) * 256 + jg * 64 + j];
  }
  __syncthreads();
#pragma unroll 1
  for (int jj = 0; jj < 16; ++jj) {
    int j = jj * 4 + wave;
    float v0 = tile[lane * 65 + j];
    float v1 = tile[(lane + 64) * 65 + j];
    float v2 = tile[(lane + 128) * 65 + j];
    bool val3 = lane < 4;
    float v3 = val3 ? tile[(lane + 192) * 65 + j] : 0.f;
    unsigned k0 = sortkey(v0), k1 = sortkey(v1), k2 = sortkey(v2);
    unsigned k3 = val3 ? sortkey(v3) : 0u;
    float thrP = radix_kth(k0, k1, k2, k3, 19);
    float thrN = radix_kth(k0, k1, k2, k3, 99);
    float spn = 0.f, spd = 0.f, snn = 0.f, snd = 0.f;
    const float invTS = 1.f / 0.03f;
#pragma unroll
    for (int q = 0; q < 4; ++q) {
      float v = (q == 0) ? v0 : (q == 1) ? v1 : (q == 2) ? v2 : v3;
      bool ok = (q < 3) || val3;
      if (ok) {
        float mp = 1.f / (1.f + __expf((thrP - v) * invTS));
        float mn = 1.f / (1.f + __expf((v - thrN) * invTS));
        spn += v * mp;
        spd += mp;
        snn += v * mn;
        snd += mn;
      }
    }
    spn = waveSum(spn); spd = waveSum(spd);
    snn = waveSum(snn); snd = waveSum(snd);
    if (lane == 0) {
      SP[i * 256 + jg * 64 + j] = spn / spd;
      SN[i * 256 + jg * 64 + j] = snn / snd;
    }
  }
}

__global__ __launch_bounds__(256) void loss12_k(const float* __restrict__ SP,
                                                const float* __restrict__ SN,
                                                float* __restrict__ out) {
  int r = blockIdx.x;
  int i = r & 255;
  bool col = r >= 256;
  int tid = threadIdx.x;
  const float invTC = 1.f / 0.07f;
  float a = (col ? SP[tid * 256 + i] : SP[i * 256 + tid]) * invTC;
  float b = (col ? SN[tid * 256 + i] : SN[i * 256 + tid]) * invTC;
  float mx = blockMax<4>(fmaxf(a, b));
  float se = blockSum<4>(__expf(a - mx) + __expf(b - mx));
  float lse = mx + __logf(se);
  if (tid == 0) {
    float diag = SP[i * 256 + i] * invTC;
    atomicAdd(out, -(diag - lse) * (1.f / 512.f));
  }
}

__global__ __launch_bounds__(256) void distcomb_k(
    const float* __restrict__ Pi, const float* __restrict__ Qj,
    const float* __restrict__ X, const float* __restrict__ V,
    float* __restrict__ val, float* __restrict__ out) {
  int i = blockIdx.x, j = threadIdx.x;
  float d = Pi[i] - 2.f * X[i * 256 + j] + Qj[j];
  float w = (i == j) ? 1.f : -V[i * 256 + j];
  float x = d * w;
  val[i * 256 + j] = x;
  __shared__ float diag_sh;
  if (j == i) diag_sh = x;
  float tot = blockSum<4>(x);
  if (j == 0) {
    float rs = diag_sh - (tot - diag_sh) * (1.f / 255.f);
    atomicAdd(out + 1, fmaxf(rs + 0.6f, 0.f) * (1.f / 512.f));
  }
}

__global__ __launch_bounds__(256) void loss4_k(const float* __restrict__ val,
                                               float* __restrict__ out) {
  int j = blockIdx.x, i = threadIdx.x;
  float x = val[i * 256 + j];
  __shared__ float diag_sh;
  if (i == j) diag_sh = x;
  float tot = blockSum<4>(x);
  if (i == 0) {
    float cs = diag_sh - (tot - diag_sh) * (1.f / 255.f);
    atomicAdd(out + 1, fmaxf(cs + 0.6f, 0.f) * (1.f / 512.f));
  }
}

// ---------------------------------------------------------------------------

extern "C" void kernel_launch(void* const* d_in, const int* in_sizes, int n_in,
                              void* d_out, int out_size, void* d_ws,
                              size_t ws_size, hipStream_t stream) {
  (void)in_sizes; (void)n_in; (void)out_size; (void)ws_size;
  const float* ev = (const float*)d_in[0];
  const float* ea = (const float*)d_in[1];
  const int* msk = (const int*)d_in[2];
  const float* Wf1 = (const float*)d_in[3];
  const float* Wf2 = (const float*)d_in[4];
  const float* Wc1 = (const float*)d_in[5];
  const float* Wc2 = (const float*)d_in[6];
  float* out = (float*)d_out;
  char* ws = (char*)d_ws;

  size_t off = 0;
  auto alloc = [&](size_t bytes) {
    void* p = ws + off;
    off = (off + bytes + 255) & ~(size_t)255;
    return p;
  };
  // Region 1: max(evb 6*RA*144 = 56.6 MB ; fv 50176*512*2 = 51.4 MB)
  unsigned short* evb = (unsigned short*)alloc((size_t)6 * RA * 144);
  unsigned short* fv = evb;  // reused after conv2
  // Region 2: max(x1b 8*RA*144 = 75.5 MB ; Sij 50176*256*4 = 51.4 MB)
  unsigned short* x1b = (unsigned short*)alloc((size_t)8 * RA * 144);
  float* Sij = (float*)x1b;  // reused after conv2
  unsigned short* wb1 = (unsigned short*)alloc((size_t)9 * 6 * 32768 * 2);
  unsigned short* wb2 = (unsigned short*)alloc((size_t)9 * 8 * 32768 * 2);
  unsigned short* eab = (unsigned short*)alloc((size_t)256 * 2048 * 2);
  unsigned short* wf1b = (unsigned short*)alloc((size_t)512 * 2048 * 2);
  unsigned short* wf2b = (unsigned short*)alloc((size_t)512 * 512 * 2);
  unsigned short* hb = (unsigned short*)alloc((size_t)256 * 512 * 2);
  float* fa = (float*)alloc((size_t)256 * 512 * 4);
  unsigned short* indnb = (unsigned short*)alloc((size_t)256 * 512 * 2);
  unsigned short* ivpb = (unsigned short*)alloc((size_t)256 * 512 * 2);
  unsigned short* fab = (unsigned short*)alloc((size_t)256 * 512 * 2);
  float* Pi = (float*)alloc(256 * 4);
  float* Qj = (float*)alloc(256 * 4);
  float* Xm = (float*)alloc((size_t)256 * 256 * 4);
  float* Vm = (float*)alloc((size_t)256 * 256 * 4);
  float* rn = (float*)alloc((size_t)50176 * 4);
  float* SP = (float*)alloc((size_t)256 * 256 * 4);
  float* SN = (float*)alloc((size_t)256 * 256 * 4);
  float* val = (float*)alloc((size_t)256 * 256 * 4);

  hipMemsetAsync(out, 0, 2 * sizeof(float), stream);

  prep_all_k<<<38656, 256, 0, stream>>>(ea, Wf1, Wf2, Wc1, Wc2, eab, wf1b,
                                        wf2b, wb1, wb2, (unsigned int*)x1b);
  evpad_k<<<dim3(256, 6), 256, 0, stream>>>(ev, evb);

  // conv1: relu, cell rows k-major (one image per block-x, N=512, K=9*384)
  convtap6_k<6, 0><<<dim3(256, 4), 256, 0, stream>>>(evb, wb1, x1b);
  // fc1 / fc2
  gemm1_k<2048, 512, 0><<<dim3(2, 4), 256, 0, stream>>>(eab, wf1b, hb, nullptr);
  gemm1_k<512, 512, 2><<<dim3(2, 4), 256, 0, stream>>>(hb, wf2b, fa, nullptr);
  // conv2: compact bf16 out (one image per block-x, N=512, K=9*512)
  convtap6_k<8, 1><<<dim3(256, 4), 256, 0, stream>>>(x1b, wb2, fv);

  pool_k<<<256, 512, 0, stream>>>(fv, msk, indnb, ivpb, Pi, rn);
  fanorm_k<<<256, 512, 0, stream>>>(fa, fab, Qj);

  // Sij[(i,p), j] = rn[i,p] * <fv[i,p,:], indn[j,:]>  (M=50176, N=256, K=512)
  gemm1_k<512, 256, 3><<<dim3(392, 2), 256, 0, stream>>>(fv, indnb, Sij, rn);
  gemm_xv_k<<<dim3(2, 2, 2), 256, 0, stream>>>(ivpb, fab, indnb, Xm, Vm);

  spsn_k<<<dim3(256, 4), 256, 0, stream>>>(Sij, SP, SN);
  loss12_k<<<512, 256, 0, stream>>>(SP, SN, out);
  distcomb_k<<<256, 256, 0, stream>>>(Pi, Qj, Xm, Vm, val, out);
  loss4_k<<<256, 256, 0, stream>>>(val, out);
}

// Round 10
// 777.408 us; speedup vs baseline: 1.0167x; 1.0167x over previous
//
#include <hip/hip_runtime.h>
#include <stdint.h>

// ---------------------------------------------------------------------------
// B=256, H=W=14, HW=196, TS=0.03, TC=0.07, TP_K=19, TN_K=98
// Conv inputs: padded 16x16 cell grid per image (1-cell zero halo):
// cell = b*256 + (h+1)*16 + (w+1). Conv 3x3 = 9 cell-row shifts d=dh*16+dw.
// convtap6_k (R8-measured structure, 759.3us total): block = ONE image
// (M 196->224) x 128 N; A window per kc = image's 256 cell rows in LDS
// (SINGLE buffer 36.9KB -> 4 blocks/CU residency with 128 VGPR; R9's 73.7KB
// dbuf halved residency AND polluted the vmcnt FIFO -> regressed, reverted).
// M-tiling: 16x16 MFMA tile = 2x8 PIXEL BLOCK (tq->dh,dw; mi->h-pair;
// wm->w-half). The pinned 1.652e7 SQ_LDS_BANK_CONFLICT = intrinsic 2-way
// wave64 b128 aliasing — benign (m136). B in per-wave REGISTERS,
// fragment-packed; b0 dbuf one step ahead; b1 at step top used after h0
// cluster; af0+af1 before h0 cluster; 9-tap loop unrolled (A tap offsets
// are ds_read immediates); s_setprio around MFMA clusters.
// R10 CHANGE — PACKED EPILOGUE STORES: within each 64-channel group, store
// channel n=ni*16+tq at slot s=tq*4+ni -> each lane's 4 outputs contiguous
// = one 8B store (28 stores/thread vs 112 x 2B; 128B contiguous per quad).
// Slot permutation compensated exactly once per consumer:
//  - x1b slots -> wb2 cin = kc*64 + (jj&3)*16 + h*8 + quad*2 + (jj>>2)
//  - fv slots  -> pool/Sij/xv are slot-consistent dots (invariant);
//    fanorm GATHERS fa[chan(slot)] so fab matches ivpb slot order.
//    Pi/Qj/rn/Sij/Vm values are permutation-invariant.
// Block mapping: DEFAULT (img=bx, n0=by*128). Grid 256x4 = exactly 4
// blocks/CU, no tail quantization.
// NOTE: workspace regions are reused; size each by the MAX of its occupants.
// ---------------------------------------------------------------------------

typedef __attribute__((ext_vector_type(8))) short bf16x8;
typedef __attribute__((ext_vector_type(4))) short short4v;
typedef __attribute__((ext_vector_type(4))) float f32x4;

__device__ __forceinline__ unsigned short f2bf(float x) {
  unsigned u = __float_as_uint(x);
  unsigned r = u + 0x7FFFu + ((u >> 16) & 1u);  // RNE, no NaNs here
  return (unsigned short)(r >> 16);
}
__device__ __forceinline__ float bf2f(unsigned short h) {
  return __uint_as_float(((unsigned)h) << 16);
}

typedef const __attribute__((address_space(1))) void* gptr1_t;
typedef __attribute__((address_space(3))) void* lptr3_t;
__device__ __forceinline__ void gload_lds16(const void* g, void* l) {
  __builtin_amdgcn_global_load_lds((gptr1_t)g, (lptr3_t)l, 16, 0, 0);
}

__device__ __forceinline__ float waveSum(float v) {
#pragma unroll
  for (int m = 1; m < 64; m <<= 1) v += __shfl_xor(v, m, 64);
  return v;
}
__device__ __forceinline__ float waveMax(float v) {
#pragma unroll
  for (int m = 1; m < 64; m <<= 1) v = fmaxf(v, __shfl_xor(v, m, 64));
  return v;
}
template <int NW>
__device__ __forceinline__ float blockSum(float v) {
  __shared__ float sh[NW];
  v = waveSum(v);
  int wv = threadIdx.x >> 6, ln = threadIdx.x & 63;
  if (ln == 0) sh[wv] = v;
  __syncthreads();
  float r = 0.f;
#pragma unroll
  for (int w = 0; w < NW; ++w) r += sh[w];
  __syncthreads();
  return r;
}
template <int NW>
__device__ __forceinline__ float blockMax(float v) {
  __shared__ float sh[NW];
  v = waveMax(v);
  int wv = threadIdx.x >> 6, ln = threadIdx.x & 63;
  if (ln == 0) sh[wv] = v;
  __syncthreads();
  float r = -3.4e38f;
#pragma unroll
  for (int w = 0; w < NW; ++w) r = fmaxf(r, sh[w]);
  __syncthreads();
  return r;
}

#define RA 65536  // rows per k-slice of conv input buffers

// ---------------------------------------------------------------------------
// convtap6_k: one image per block-x. C[p,n] = sum_t sum_k A[cell(p)+d_t,k]B[t,n,k]
// 256 thr, 4 waves (wm in {0,1}: w-half, wn in {0,1}: 64 cols), acc 7x4 of
// 16x16x32 bf16 MFMA. A: [kc][RA][72] shorts (LDS window 256x72 = 36.9 KB).
// B: fragment-packed [t][kc][g(32)][h(2)][lane(64)][8] shorts, reg-loaded.
// EPI 0: relu -> x1b (cell rows, SLOT-packed). EPI 1: bf16 -> fv (SLOT-packed).
// ---------------------------------------------------------------------------
template <int KC, int EPI>
__global__ __launch_bounds__(256, 2) void convtap6_k(
    const unsigned short* __restrict__ A, const unsigned short* __restrict__ Bw,
    unsigned short* __restrict__ C) {
  __shared__ __align__(16) short Ah[256 * 72];
  const int tid = threadIdx.x;
  const int wave = tid >> 6, lane = tid & 63;
  const int wm = wave >> 1, wn = wave & 1;
  const int quad = lane >> 4, tq = lane & 15;
  const int img = blockIdx.x, n0 = blockIdx.y * 128;

  // A BYTE-base per mi, biased -17 rows so every tap offset immediate >= 0:
  // read addr = pab[mi] + OFF(t,h), OFF = (17+(dh-1)*16+(dw-1))*144 + h*64.
  int pab[7];
  {
    const int dh = tq >> 3;
    int wq = wm * 8 + (tq & 7);          // w' in 0..15
    if (wq == 0) wq = 8;                 // dead col -> mirrored valid col
    else if (wq == 15) wq = 7;
#pragma unroll
    for (int mi = 0; mi < 7; ++mi) {
      int pr = (1 + 2 * mi + dh) * 16 + wq;   // 17..239
      pab[mi] = (pr - 17) * 144 + quad * 16;  // bytes
    }
  }
  // B fragment base (shorts): (t*KC+kc)*32768 + g*1024 + h*512 + lane*8
  const int gb = (n0 >> 4) + wn * 4;

  const char* Ab = (const char*)A;
  const char* AhB = (const char*)Ah;
  const int l16 = lane * 16;

  f32x4 acc[7][4];
#pragma unroll
  for (int mi = 0; mi < 7; ++mi)
#pragma unroll
    for (int ni = 0; ni < 4; ++ni) {
      f32x4 z = {0.f, 0.f, 0.f, 0.f};
      acc[mi][ni] = z;
    }

  auto stageA = [&](int kc) {
    size_t s0 = ((size_t)kc * RA + img * 256) * 144;
#pragma unroll
    for (int i = 0; i < 9; ++i) {
      int c = wave + i * 4;  // 36 chunks of 1024 B
      gload_lds16(Ab + s0 + (size_t)c * 1024 + l16, (char*)Ah + c * 1024);
    }
  };

  stageA(0);
  bf16x8 b0[4], b1[4];
  {  // h0 frags of (kc=0,t=0): overlaps A staging + barrier
    const size_t w0 = ((size_t)gb * 128 + lane) * 8;
#pragma unroll
    for (int ni = 0; ni < 4; ++ni)
      b0[ni] = *(const bf16x8*)&Bw[w0 + (size_t)ni * 1024];
  }
  __syncthreads();

#pragma unroll 1
  for (int kc = 0; kc < KC; ++kc) {
    const size_t bk = ((size_t)kc * 4096 + gb * 128 + lane) * 8;  // shorts
#pragma unroll
    for (int t = 0; t < 9; ++t) {
      const size_t tof = (size_t)t * KC * 32768;  // compile-time
      // h1 frags of this step: used after the h0 cluster (~650 cyc)
#pragma unroll
      for (int ni = 0; ni < 4; ++ni)
        b1[ni] = *(const bf16x8*)&Bw[bk + tof + (size_t)ni * 1024 + 512];
      // prefetch next step's h0 frags (~full step of cover)
      bf16x8 b0n[4];
      const bool last = (t == 8) && (kc == KC - 1);
      if (!last) {
        const size_t nbase =
            (t < 8) ? bk + (size_t)(t + 1) * KC * 32768 : bk + 32768;
#pragma unroll
        for (int ni = 0; ni < 4; ++ni)
          b0n[ni] = *(const bf16x8*)&Bw[nbase + (size_t)ni * 1024];
      }
      // A fragments: base reg + CONSTANT offset (folds into ds_read imm)
      const int OFF = (17 + (t / 3 - 1) * 16 + (t % 3 - 1)) * 144;
      bf16x8 af0[7], af1[7];
#pragma unroll
      for (int mi = 0; mi < 7; ++mi)
        af0[mi] = *(const bf16x8*)(AhB + pab[mi] + OFF);
#pragma unroll
      for (int mi = 0; mi < 7; ++mi)
        af1[mi] = *(const bf16x8*)(AhB + pab[mi] + OFF + 64);
      __builtin_amdgcn_s_setprio(1);
#pragma unroll
      for (int mi = 0; mi < 7; ++mi)
#pragma unroll
        for (int ni = 0; ni < 4; ++ni)
          acc[mi][ni] = __builtin_amdgcn_mfma_f32_16x16x32_bf16(
              af0[mi], b0[ni], acc[mi][ni], 0, 0, 0);
#pragma unroll
      for (int mi = 0; mi < 7; ++mi)
#pragma unroll
        for (int ni = 0; ni < 4; ++ni)
          acc[mi][ni] = __builtin_amdgcn_mfma_f32_16x16x32_bf16(
              af1[mi], b1[ni], acc[mi][ni], 0, 0, 0);
      __builtin_amdgcn_s_setprio(0);
      if (!last) {
#pragma unroll
        for (int ni = 0; ni < 4; ++ni) b0[ni] = b0n[ni];  // SSA rename, free
      }
    }
    if (kc + 1 < KC) {  // A window restage at kc boundary (hidden by the
      __syncthreads();  // 3 co-resident blocks' compute — R8/R9 A/B result)
      stageA(kc + 1);
      __syncthreads();
    }
  }

  // Packed epilogue: slot s = tq*4+ni within the 64-col group -> one 8B
  // store per (mi,r); each quad writes a contiguous 128B run.
#pragma unroll
  for (int mi = 0; mi < 7; ++mi) {
#pragma unroll
    for (int r = 0; r < 4; ++r) {
      int idx = quad * 4 + r;            // M-row within tile, 0..15
      int wv = wm * 8 + (idx & 7);       // w' in 0..15
      if (wv == 0 || wv == 15) continue;  // dead column (halo)
      int hh = 1 + 2 * mi + (idx >> 3);  // h' in 1..14
      short4v s4;
#pragma unroll
      for (int ni = 0; ni < 4; ++ni) {
        float v = acc[mi][ni][r];
        s4[ni] = (short)f2bf(EPI == 0 ? fmaxf(v, 0.f) : v);
      }
      if (EPI == 0) {
        int cell = img * 256 + hh * 16 + wv;
        int slice = (n0 >> 6) + wn;
        size_t ob = ((size_t)slice * RA + cell) * 72 + tq * 4;
        *(short4v*)&C[ob] = s4;
      } else {
        int p = (hh - 1) * 14 + (wv - 1);
        size_t ob = (size_t)(img * 196 + p) * 512 + n0 + wn * 64 + tq * 4;
        *(short4v*)&C[ob] = s4;
      }
    }
  }
}

// ---------------------------------------------------------------------------
// gemm1_k: C[m,n] = sum_k A[m,k]*B[n,k]; 128x128 tile, 4 waves, BK=64,
// XOR-swizzled LDS. EPI: 0 relu->bf16, 2 f32, 3 f32 * rs[m] (row scale).
// ---------------------------------------------------------------------------
template <int K, int NLD, int EPI>
__global__ __launch_bounds__(256, 2) void gemm1_k(
    const unsigned short* __restrict__ A, const unsigned short* __restrict__ Bw,
    void* __restrict__ C, const float* __restrict__ rs) {
  __shared__ short As[128 * 64];
  __shared__ short Bs[128 * 64];
  const int tid = threadIdx.x;
  const int wave = tid >> 6, lane = tid & 63;
  const int m0 = blockIdx.x * 128, n0 = blockIdx.y * 128;
  const int rr8 = lane >> 3, seg = lane & 7, gseg = seg ^ rr8;
  const int wm = wave >> 1, wn = wave & 1;
  const int quad = lane >> 4, tq = lane & 15;

  size_t asrc[4], bsrc[4];
#pragma unroll
  for (int i8 = 0; i8 < 4; ++i8) {
    int rloc = wave * 32 + i8 * 8 + rr8;
    asrc[i8] = (size_t)(m0 + rloc) * K + gseg * 8;
    bsrc[i8] = (size_t)(n0 + rloc) * K + gseg * 8;
  }

  f32x4 acc[4][4];
#pragma unroll
  for (int mi = 0; mi < 4; ++mi)
#pragma unroll
    for (int ni = 0; ni < 4; ++ni) {
      f32x4 z = {0.f, 0.f, 0.f, 0.f};
      acc[mi][ni] = z;
    }

#pragma unroll 1
  for (int kc2 = 0; kc2 < K / 64; ++kc2) {
    int kb = kc2 * 64;
    __syncthreads();
#pragma unroll
    for (int i8 = 0; i8 < 4; ++i8) {
      gload_lds16(A + asrc[i8] + kb, &As[(wave * 32 + i8 * 8) * 64]);
      gload_lds16(Bw + bsrc[i8] + kb, &Bs[(wave * 32 + i8 * 8) * 64]);
    }
    __syncthreads();
#pragma unroll
    for (int h = 0; h < 2; ++h) {
      bf16x8 af[4], bfr[4];
#pragma unroll
      for (int mi = 0; mi < 4; ++mi) {
        int row = wm * 64 + mi * 16 + tq;
        af[mi] = *(const bf16x8*)&As[row * 64 +
                                     ((((h << 2) | quad) ^ (row & 7)) << 3)];
      }
#pragma unroll
      for (int ni = 0; ni < 4; ++ni) {
        int row = wn * 64 + ni * 16 + tq;
        bfr[ni] = *(const bf16x8*)&Bs[row * 64 +
                                      ((((h << 2) | quad) ^ (row & 7)) << 3)];
      }
#pragma unroll
      for (int mi = 0; mi < 4; ++mi)
#pragma unroll
        for (int ni = 0; ni < 4; ++ni)
          acc[mi][ni] = __builtin_amdgcn_mfma_f32_16x16x32_bf16(
              af[mi], bfr[ni], acc[mi][ni], 0, 0, 0);
    }
  }

#pragma unroll
  for (int mi = 0; mi < 4; ++mi) {
#pragma unroll
    for (int r = 0; r < 4; ++r) {
      int m = m0 + wm * 64 + mi * 16 + quad * 4 + r;
      float sc = (EPI == 3) ? rs[m] : 1.f;
      size_t obase = (size_t)m * NLD + n0 + wn * 64 + tq;
#pragma unroll
      for (int ni = 0; ni < 4; ++ni) {
        float v = acc[mi][ni][r];
        size_t idx = obase + ni * 16;
        if (EPI == 0)
          ((unsigned short*)C)[idx] = f2bf(fmaxf(v, 0.f));
        else if (EPI == 2)
          ((float*)C)[idx] = v;
        else
          ((float*)C)[idx] = v * sc;
      }
    }
  }
}

// Xm = (iv+eps).fa^T and Vm = indn.indn^T in one dispatch (blockIdx.z picks)
__global__ __launch_bounds__(256, 2) void gemm_xv_k(
    const unsigned short* __restrict__ ivpb, const unsigned short* __restrict__ fab,
    const unsigned short* __restrict__ indnb, float* __restrict__ Xm,
    float* __restrict__ Vm) {
  const unsigned short* A = blockIdx.z ? indnb : ivpb;
  const unsigned short* Bw = blockIdx.z ? indnb : fab;
  float* C = blockIdx.z ? Vm : Xm;
  __shared__ short As[128 * 64];
  __shared__ short Bs[128 * 64];
  const int tid = threadIdx.x;
  const int wave = tid >> 6, lane = tid & 63;
  const int m0 = blockIdx.x * 128, n0 = blockIdx.y * 128;
  const int rr8 = lane >> 3, seg = lane & 7, gseg = seg ^ rr8;
  const int wm = wave >> 1, wn = wave & 1;
  const int quad = lane >> 4, tq = lane & 15;
  size_t asrc[4], bsrc[4];
#pragma unroll
  for (int i8 = 0; i8 < 4; ++i8) {
    int rloc = wave * 32 + i8 * 8 + rr8;
    asrc[i8] = (size_t)(m0 + rloc) * 512 + gseg * 8;
    bsrc[i8] = (size_t)(n0 + rloc) * 512 + gseg * 8;
  }
  f32x4 acc[4][4];
#pragma unroll
  for (int mi = 0; mi < 4; ++mi)
#pragma unroll
    for (int ni = 0; ni < 4; ++ni) {
      f32x4 z = {0.f, 0.f, 0.f, 0.f};
      acc[mi][ni] = z;
    }
#pragma unroll 1
  for (int kc2 = 0; kc2 < 8; ++kc2) {
    int kb = kc2 * 64;
    __syncthreads();
#pragma unroll
    for (int i8 = 0; i8 < 4; ++i8) {
      gload_lds16(A + asrc[i8] + kb, &As[(wave * 32 + i8 * 8) * 64]);
      gload_lds16(Bw + bsrc[i8] + kb, &Bs[(wave * 32 + i8 * 8) * 64]);
    }
    __syncthreads();
#pragma unroll
    for (int h = 0; h < 2; ++h) {
      bf16x8 af[4], bfr[4];
#pragma unroll
      for (int mi = 0; mi < 4; ++mi) {
        int row = wm * 64 + mi * 16 + tq;
        af[mi] = *(const bf16x8*)&As[row * 64 +
                                     ((((h << 2) | quad) ^ (row & 7)) << 3)];
      }
#pragma unroll
      for (int ni = 0; ni < 4; ++ni) {
        int row = wn * 64 + ni * 16 + tq;
        bfr[ni] = *(const bf16x8*)&Bs[row * 64 +
                                      ((((h << 2) | quad) ^ (row & 7)) << 3)];
      }
#pragma unroll
      for (int mi = 0; mi < 4; ++mi)
#pragma unroll
        for (int ni = 0; ni < 4; ++ni)
          acc[mi][ni] = __builtin_amdgcn_mfma_f32_16x16x32_bf16(
              af[mi], bfr[ni], acc[mi][ni], 0, 0, 0);
    }
  }
#pragma unroll
  for (int mi = 0; mi < 4; ++mi)
#pragma unroll
    for (int r = 0; r < 4; ++r) {
      int m = m0 + wm * 64 + mi * 16 + quad * 4 + r;
      size_t obase = (size_t)m * 256 + n0 + wn * 64 + tq;
#pragma unroll
      for (int ni = 0; ni < 4; ++ni) C[obase + ni * 16] = acc[mi][ni][r];
    }
}

// --------------------------- prep (fused) ----------------------------------
// ranges: ea/Wf1/Wf2 casts | wb1 build | wb2 build | x1b halo zeroing
// wb layout (fragment-packed): flat index j =
//   (((t*KC+kc)*32 + g)*2 + h)*512 + quad*128 + tq*8 + jj,  n = g*16+tq.
// wb1 (conv1, input=evb identity channels): cin = kc*64 + h*32 + quad*8 + jj
// wb2 (conv2, input=x1b SLOT-packed by conv1's epilogue): A k-slot p64 =
//   h*32+quad*8+jj holds conv1 channel (p64&3)*16 + (p64>>2)
//   -> cin = kc*64 + (jj&3)*16 + h*8 + quad*2 + (jj>>2).
__global__ void prep_all_k(const float* __restrict__ ea,
                           const float* __restrict__ Wf1,
                           const float* __restrict__ Wf2,
                           const float* __restrict__ Wc1,
                           const float* __restrict__ Wc2,
                           unsigned short* __restrict__ eab,
                           unsigned short* __restrict__ wf1b,
                           unsigned short* __restrict__ wf2b,
                           unsigned short* __restrict__ wb1,
                           unsigned short* __restrict__ wb2,
                           unsigned int* __restrict__ x1u) {
  int i = blockIdx.x * 256 + threadIdx.x;
  if (i < 524288) {
    eab[i] = f2bf(ea[i]);
  } else if (i < 1572864) {
    int j = i - 524288;
    wf1b[j] = f2bf(Wf1[j]);
  } else if (i < 1835008) {
    int j = i - 1572864;
    wf2b[j] = f2bf(Wf2[j]);
  } else if (i < 3604480) {
    int j = i - 1835008;  // wb1: 9*6*32768 fragment-packed <- Wc1[n][384][3][3]
    int t = j / (6 * 32768), r = j - t * (6 * 32768);
    int kc = r / 32768, r2 = r - kc * 32768;
    int g = r2 >> 10, h = (r2 >> 9) & 1, quad = (r2 >> 7) & 3;
    int tq = (r2 >> 3) & 15, jj = r2 & 7;
    int n = g * 16 + tq, cin = kc * 64 + h * 32 + quad * 8 + jj;
    wb1[j] = f2bf(Wc1[(n * 384 + cin) * 9 + t]);
  } else if (i < 5963776) {
    int j = i - 3604480;  // wb2: 9*8*32768 fragment-packed <- Wc2[n][512][3][3]
    int t = j / (8 * 32768), r = j - t * (8 * 32768);
    int kc = r / 32768, r2 = r - kc * 32768;
    int g = r2 >> 10, h = (r2 >> 9) & 1, quad = (r2 >> 7) & 3;
    int tq = (r2 >> 3) & 15, jj = r2 & 7;
    int n = g * 16 + tq;
    int cin = kc * 64 + (jj & 3) * 16 + h * 8 + quad * 2 + (jj >> 2);
    wb2[j] = f2bf(Wc2[(n * 512 + cin) * 9 + t]);
  } else {
    int j = i - 5963776;  // 15360 halo rows x 8 slices x 32 uints
    int hr = j >> 8, u = j & 255;
    int slice = u >> 5, uu = u & 31;
    int b = hr / 60, c = hr - b * 60;
    int cell;
    if (c < 16) cell = c;
    else if (c < 32) cell = 240 + (c - 16);
    else if (c < 46) cell = (c - 31) * 16;
    else cell = (c - 45) * 16 + 15;
    x1u[((size_t)slice * RA + b * 256 + cell) * 36 + uu] = 0u;
  }
}

// ev (256,384,14,14) fp32 -> evb [kc6][RA][72] bf16 (halo cells zero)
__global__ __launch_bounds__(256) void evpad_k(const float* __restrict__ ev,
                                               unsigned short* __restrict__ out) {
  int b = blockIdx.x, ct = blockIdx.y;  // channel tile: c0 = ct*64
  __shared__ float tile[64][197];
  int tid = threadIdx.x;
  const float* src = ev + ((size_t)b * 384 + ct * 64) * 196;
#pragma unroll 1
  for (int it = 0; it < 49; ++it) {
    int idx = it * 256 + tid;
    int c = idx / 196, p = idx - c * 196;
    tile[c][p] = src[idx];
  }
  __syncthreads();
  unsigned short* dst = out + ((size_t)ct * RA + b * 256) * 72;
#pragma unroll 1
  for (int it = 0; it < 64; ++it) {
    int idx = it * 256 + tid;
    int cell = idx >> 6, c = idx & 63;
    int h = (cell >> 4) - 1, w = (cell & 15) - 1;
    float v = ((unsigned)h < 14u && (unsigned)w < 14u) ? tile[c][h * 14 + w]
                                                       : 0.f;
    dst[(size_t)cell * 72 + c] = f2bf(v);
  }
}

// --------------------------- pooling / norms -------------------------------

// fused: masked mean pool + per-pixel inverse norm (rn) + ind normalization
// fv is SLOT-packed; all sums here are slot-permutation-invariant, and
// indnb/ivpb inherit slot order (consistent with fv/fab in later dots).
__global__ __launch_bounds__(512) void pool_k(
    const unsigned short* __restrict__ fv, const int* __restrict__ masks,
    unsigned short* __restrict__ indnb, unsigned short* __restrict__ ivpb,
    float* __restrict__ Pi, float* __restrict__ rn) {
  int b = blockIdx.x;
  int w = threadIdx.x >> 6, lane = threadIdx.x & 63;
  __shared__ float red[8][512];
  __shared__ float msh[8];
  float acc[8] = {0.f, 0.f, 0.f, 0.f, 0.f, 0.f, 0.f, 0.f};
  float msum = 0.f;
  for (int p = w; p < 196; p += 8) {
    float m = (float)masks[b * 196 + p];
    msum += m;
    uint4 d = *(const uint4*)(fv + (size_t)(b * 196 + p) * 512 + lane * 8);
    const unsigned short* hp = (const unsigned short*)&d;
    float ss = 0.f;
#pragma unroll
    for (int k = 0; k < 8; ++k) {
      float x = bf2f(hp[k]);
      ss += x * x;
      acc[k] += m * x;
    }
    ss = waveSum(ss);
    if (lane == 0) rn[b * 196 + p] = 1.f / fmaxf(sqrtf(ss), 1e-12f);
  }
#pragma unroll
  for (int k = 0; k < 8; ++k) red[w][lane * 8 + k] = acc[k];
  if (lane == 0) msh[w] = msum;
  __syncthreads();
  int tid = threadIdx.x;
  float s = 0.f, mtot = 0.f;
#pragma unroll
  for (int ww = 0; ww < 8; ++ww) {
    s += red[ww][tid];
    mtot += msh[ww];
  }
  float v = s / mtot;  // indv[b, slot tid]
  float ss2 = blockSum<8>(v * v);
  float sc = 1.f / fmaxf(sqrtf(ss2), 1e-12f);
  indnb[b * 512 + tid] = f2bf(v * sc);
  float ve = v + 1e-6f;
  ivpb[b * 512 + tid] = f2bf(ve);
  float p2 = blockSum<8>(ve * ve);
  if (tid == 0) Pi[b] = p2;
}

// fa fp32 -> fab bf16 in SLOT order (gather chan(slot)) + Qj = ||fa_j||^2.
// slot s (within 64-group): channel = (s&3)*16 + (s>>2).
__global__ __launch_bounds__(512) void fanorm_k(const float* __restrict__ fa,
                                                unsigned short* __restrict__ fab,
                                                float* __restrict__ Qj) {
  int b = blockIdx.x, tid = threadIdx.x;
  int s64 = tid & 63;
  int chan = (tid & ~63) | ((s64 & 3) * 16 + (s64 >> 2));
  float v = fa[b * 512 + chan];
  fab[b * 512 + tid] = f2bf(v);
  float q = blockSum<8>(v * v);  // permutation-invariant
  if (tid == 0) Qj[b] = q;
}

// ------------------------------ SP / SN ------------------------------------

__device__ __forceinline__ float radix_kth(unsigned k0, unsigned k1, unsigned k2,
                                           unsigned k3, int k) {
  unsigned prefix = 0;
  int kk = k;
#pragma unroll 1
  for (int bit = 31; bit >= 14; --bit) {  // 18 steps; thr err ~2^-9 rel, ok
    unsigned thi = (prefix >> bit) | 1u;
    int c = __popcll(__ballot((k0 >> bit) == thi)) +
            __popcll(__ballot((k1 >> bit) == thi)) +
            __popcll(__ballot((k2 >> bit) == thi)) +
            __popcll(__ballot((k3 >> bit) == thi));
    if (kk <= c)
      prefix |= (1u << bit);
    else
      kk -= c;
  }
  unsigned u = (prefix & 0x80000000u) ? (prefix ^ 0x80000000u) : ~prefix;
  return __uint_as_float(u);
}
__device__ __forceinline__ unsigned sortkey(float x) {
  unsigned u = __float_as_uint(x);
  return u ^ (((int)u >> 31) | 0x80000000u);
}

__global__ __launch_bounds__(256) void spsn_k(const float* __restrict__ Sij,
                                              float* __restrict__ SP,
                                              float* __restrict__ SN) {
  int i = blockIdx.x, jg = blockIdx.y;
  int tid = threadIdx.x, wave = tid >> 6, lane = tid & 63;
  __shared__ float tile[196 * 65];
#pragma unroll 1
  for (int it = 0; it < 49; ++it) {
    int lin = it * 256 + tid;
    int p = lin >> 6, j = lin & 63;
    tile[p * 65 + j] = Sij[(size_t)(i * 196 + p) * 256 + jg * 64 + j];
  }
  __syncthreads();
#pragma unroll 1
  for (int jj = 0; jj < 16; ++jj) {
    int j = jj * 4 + wave;
    float v0 = tile[lane * 65 + j];
    float v1 = tile[(lane + 64) * 65 + j];
    float v2 = tile[(lane + 128) * 65 + j];
    bool val3 = lane < 4;
    float v3 = val3 ? tile[(lane + 192) * 65 + j] : 0.f;
    unsigned k0 = sortkey(v0), k1 = sortkey(v1), k2 = sortkey(v2);
    unsigned k3 = val3 ? sortkey(v3) : 0u;
    float thrP = radix_kth(k0, k1, k2, k3, 19);
    float thrN = radix_kth(k0, k1, k2, k3, 99);
    float spn = 0.f, spd = 0.f, snn = 0.f, snd = 0.f;
    const float invTS = 1.f / 0.03f;
#pragma unroll
    for (int q = 0; q < 4; ++q) {
      float v = (q == 0) ? v0 : (q == 1) ? v1 : (q == 2) ? v2 : v3;
      bool ok = (q < 3) || val3;
      if (ok) {
        float mp = 1.f / (1.f + __expf((thrP - v) * invTS));
        float mn = 1.f / (1.f + __expf((v - thrN) * invTS));
        spn += v * mp;
        spd += mp;
        snn += v * mn;
        snd += mn;
      }
    }
    spn = waveSum(spn); spd = waveSum(spd);
    snn = waveSum(snn); snd = waveSum(snd);
    if (lane == 0) {
      SP[i * 256 + jg * 64 + j] = spn / spd;
      SN[i * 256 + jg * 64 + j] = snn / snd;
    }
  }
}

__global__ __launch_bounds__(256) void loss12_k(const float* __restrict__ SP,
                                                const float* __restrict__ SN,
                                                float* __restrict__ out) {
  int r = blockIdx.x;
  int i = r & 255;
  bool col = r >= 256;
  int tid = threadIdx.x;
  const float invTC = 1.f / 0.07f;
  float a = (col ? SP[tid * 256 + i] : SP[i * 256 + tid]) * invTC;
  float b = (col ? SN[tid * 256 + i] : SN[i * 256 + tid]) * invTC;
  float mx = blockMax<4>(fmaxf(a, b));
  float se = blockSum<4>(__expf(a - mx) + __expf(b - mx));
  float lse = mx + __logf(se);
  if (tid == 0) {
    float diag = SP[i * 256 + i] * invTC;
    atomicAdd(out, -(diag - lse) * (1.f / 512.f));
  }
}

__global__ __launch_bounds__(256) void distcomb_k(
    const float* __restrict__ Pi, const float* __restrict__ Qj,
    const float* __restrict__ X, const float* __restrict__ V,
    float* __restrict__ val, float* __restrict__ out) {
  int i = blockIdx.x, j = threadIdx.x;
  float d = Pi[i] - 2.f * X[i * 256 + j] + Qj[j];
  float w = (i == j) ? 1.f : -V[i * 256 + j];
  float x = d * w;
  val[i * 256 + j] = x;
  __shared__ float diag_sh;
  if (j == i) diag_sh = x;
  float tot = blockSum<4>(x);
  if (j == 0) {
    float rs = diag_sh - (tot - diag_sh) * (1.f / 255.f);
    atomicAdd(out + 1, fmaxf(rs + 0.6f, 0.f) * (1.f / 512.f));
  }
}

__global__ __launch_bounds__(256) void loss4_k(const float* __restrict__ val,
                                               float* __restrict__ out) {
  int j = blockIdx.x, i = threadIdx.x;
  float x = val[i * 256 + j];
  __shared__ float diag_sh;
  if (i == j) diag_sh = x;
  float tot = blockSum<4>(x);
  if (i == 0) {
    float cs = diag_sh - (tot - diag_sh) * (1.f / 255.f);
    atomicAdd(out + 1, fmaxf(cs + 0.6f, 0.f) * (1.f / 512.f));
  }
}

// ---------------------------------------------------------------------------

extern "C" void kernel_launch(void* const* d_in, const int* in_sizes, int n_in,
                              void* d_out, int out_size, void* d_ws,
                              size_t ws_size, hipStream_t stream) {
  (void)in_sizes; (void)n_in; (void)out_size; (void)ws_size;
  const float* ev = (const float*)d_in[0];
  const float* ea = (const float*)d_in[1];
  const int* msk = (const int*)d_in[2];
  const float* Wf1 = (const float*)d_in[3];
  const float* Wf2 = (const float*)d_in[4];
  const float* Wc1 = (const float*)d_in[5];
  const float* Wc2 = (const float*)d_in[6];
  float* out = (float*)d_out;
  char* ws = (char*)d_ws;

  size_t off = 0;
  auto alloc = [&](size_t bytes) {
    void* p = ws + off;
    off = (off + bytes + 255) & ~(size_t)255;
    return p;
  };
  // Region 1: max(evb 6*RA*144 = 56.6 MB ; fv 50176*512*2 = 51.4 MB)
  unsigned short* evb = (unsigned short*)alloc((size_t)6 * RA * 144);
  unsigned short* fv = evb;  // reused after conv2
  // Region 2: max(x1b 8*RA*144 = 75.5 MB ; Sij 50176*256*4 = 51.4 MB)
  unsigned short* x1b = (unsigned short*)alloc((size_t)8 * RA * 144);
  float* Sij = (float*)x1b;  // reused after conv2
  unsigned short* wb1 = (unsigned short*)alloc((size_t)9 * 6 * 32768 * 2);
  unsigned short* wb2 = (unsigned short*)alloc((size_t)9 * 8 * 32768 * 2);
  unsigned short* eab = (unsigned short*)alloc((size_t)256 * 2048 * 2);
  unsigned short* wf1b = (unsigned short*)alloc((size_t)512 * 2048 * 2);
  unsigned short* wf2b = (unsigned short*)alloc((size_t)512 * 512 * 2);
  unsigned short* hb = (unsigned short*)alloc((size_t)256 * 512 * 2);
  float* fa = (float*)alloc((size_t)256 * 512 * 4);
  unsigned short* indnb = (unsigned short*)alloc((size_t)256 * 512 * 2);
  unsigned short* ivpb = (unsigned short*)alloc((size_t)256 * 512 * 2);
  unsigned short* fab = (unsigned short*)alloc((size_t)256 * 512 * 2);
  float* Pi = (float*)alloc(256 * 4);
  float* Qj = (float*)alloc(256 * 4);
  float* Xm = (float*)alloc((size_t)256 * 256 * 4);
  float* Vm = (float*)alloc((size_t)256 * 256 * 4);
  float* rn = (float*)alloc((size_t)50176 * 4);
  float* SP = (float*)alloc((size_t)256 * 256 * 4);
  float* SN = (float*)alloc((size_t)256 * 256 * 4);
  float* val = (float*)alloc((size_t)256 * 256 * 4);

  hipMemsetAsync(out, 0, 2 * sizeof(float), stream);

  prep_all_k<<<38656, 256, 0, stream>>>(ea, Wf1, Wf2, Wc1, Wc2, eab, wf1b,
                                        wf2b, wb1, wb2, (unsigned int*)x1b);
  evpad_k<<<dim3(256, 6), 256, 0, stream>>>(ev, evb);

  // conv1: relu, cell rows k-major (one image per block-x, N=512, K=9*384)
  convtap6_k<6, 0><<<dim3(256, 4), 256, 0, stream>>>(evb, wb1, x1b);
  // fc1 / fc2
  gemm1_k<2048, 512, 0><<<dim3(2, 4), 256, 0, stream>>>(eab, wf1b, hb, nullptr);
  gemm1_k<512, 512, 2><<<dim3(2, 4), 256, 0, stream>>>(hb, wf2b, fa, nullptr);
  // conv2: compact bf16 out (one image per block-x, N=512, K=9*512)
  convtap6_k<8, 1><<<dim3(256, 4), 256, 0, stream>>>(x1b, wb2, fv);

  pool_k<<<256, 512, 0, stream>>>(fv, msk, indnb, ivpb, Pi, rn);
  fanorm_k<<<256, 512, 0, stream>>>(fa, fab, Qj);

  // Sij[(i,p), j] = rn[i,p] * <fv[i,p,:], indn[j,:]>  (M=50176, N=256, K=512)
  gemm1_k<512, 256, 3><<<dim3(392, 2), 256, 0, stream>>>(fv, indnb, Sij, rn);
  gemm_xv_k<<<dim3(2, 2, 2), 256, 0, stream>>>(ivpb, fab, indnb, Xm, Vm);

  spsn_k<<<dim3(256, 4), 256, 0, stream>>>(Sij, SP, SN);
  loss12_k<<<512, 256, 0, stream>>>(SP, SN, out);
  distcomb_k<<<256, 256, 0, stream>>>(Pi, Qj, Xm, Vm, val, out);
  loss4_k<<<256, 256, 0, stream>>>(val, out);
}

// Round 11
// 764.024 us; speedup vs baseline: 1.0345x; 1.0175x over previous
//
#include <hip/hip_runtime.h>
#include <stdint.h>

// ---------------------------------------------------------------------------
// B=256, H=W=14, HW=196, TS=0.03, TC=0.07, TP_K=19, TN_K=98
// Conv inputs: padded 16x16 cell grid per image (1-cell zero halo):
// cell = b*256 + (h+1)*16 + (w+1). Conv 3x3 = 9 cell-row shifts d=dh*16+dw.
// convtap6_k (R8/R10-measured, FROZEN): block = ONE image x 128 N; A window
// per kc in single-buffer LDS (36.9KB, 4 blocks/CU); B in per-wave regs,
// fragment-packed, b0 dbuf one step ahead, b1 at step top; 9-tap loop
// unrolled (A tap offsets = ds_read immediates); setprio around MFMA;
// packed slot epilogue (s=tq*4+ni -> one 8B store per (mi,r)).
// Measured: conv1~conv2~204us, MfmaUtil 61%, VALUBusy 19.5%. The pinned
// 1.652e7 SQ_LDS_BANK_CONFLICT = intrinsic 2-way wave64 b128 alias (benign).
// R11 CHANGE — TAIL (convs untouched): total 777 = 406 conv + ~370 tail.
//  (a) gemm1_k/gemm_xv_k: LDS DOUBLE-BUFFER staging (stage next kc before
//      compute; ONE barrier/iter). fc1 is 8 blocks x 32 serial K-steps of
//      sync->stage->sync->compute = pure exposed latency (T14's regime:
//      latency-bound low-TLP — where dbuf DOES pay, unlike conv R9).
//      LDS 32->64KB, still 2 blocks/CU (Sij gemm unaffected).
//  (b) pool+fanorm fused (grid 512, role by blockIdx).
//  (c) loss12+distcomb fused (grid 768). 14 -> 12 dispatches.
// Slot permutation (R10) unchanged: wb2 cin remap; fanorm gathers chan(slot);
// all other consumers are slot-invariant dots.
// NOTE: workspace regions are reused; size each by the MAX of its occupants.
// ---------------------------------------------------------------------------

typedef __attribute__((ext_vector_type(8))) short bf16x8;
typedef __attribute__((ext_vector_type(4))) short short4v;
typedef __attribute__((ext_vector_type(4))) float f32x4;

__device__ __forceinline__ unsigned short f2bf(float x) {
  unsigned u = __float_as_uint(x);
  unsigned r = u + 0x7FFFu + ((u >> 16) & 1u);  // RNE, no NaNs here
  return (unsigned short)(r >> 16);
}
__device__ __forceinline__ float bf2f(unsigned short h) {
  return __uint_as_float(((unsigned)h) << 16);
}

typedef const __attribute__((address_space(1))) void* gptr1_t;
typedef __attribute__((address_space(3))) void* lptr3_t;
__device__ __forceinline__ void gload_lds16(const void* g, void* l) {
  __builtin_amdgcn_global_load_lds((gptr1_t)g, (lptr3_t)l, 16, 0, 0);
}

__device__ __forceinline__ float waveSum(float v) {
#pragma unroll
  for (int m = 1; m < 64; m <<= 1) v += __shfl_xor(v, m, 64);
  return v;
}
__device__ __forceinline__ float waveMax(float v) {
#pragma unroll
  for (int m = 1; m < 64; m <<= 1) v = fmaxf(v, __shfl_xor(v, m, 64));
  return v;
}
template <int NW>
__device__ __forceinline__ float blockSum(float v) {
  __shared__ float sh[NW];
  v = waveSum(v);
  int wv = threadIdx.x >> 6, ln = threadIdx.x & 63;
  if (ln == 0) sh[wv] = v;
  __syncthreads();
  float r = 0.f;
#pragma unroll
  for (int w = 0; w < NW; ++w) r += sh[w];
  __syncthreads();
  return r;
}
template <int NW>
__device__ __forceinline__ float blockMax(float v) {
  __shared__ float sh[NW];
  v = waveMax(v);
  int wv = threadIdx.x >> 6, ln = threadIdx.x & 63;
  if (ln == 0) sh[wv] = v;
  __syncthreads();
  float r = -3.4e38f;
#pragma unroll
  for (int w = 0; w < NW; ++w) r = fmaxf(r, sh[w]);
  __syncthreads();
  return r;
}

#define RA 65536  // rows per k-slice of conv input buffers

// ---------------------------------------------------------------------------
// convtap6_k: one image per block-x. C[p,n] = sum_t sum_k A[cell(p)+d_t,k]B[t,n,k]
// 256 thr, 4 waves (wm: w-half, wn: 64-col half), acc 7x4 of 16x16x32 bf16
// MFMA. A: [kc][RA][72] shorts (LDS 256x72 = 36.9 KB). B: fragment-packed
// [t][kc][g(32)][h(2)][lane(64)][8] shorts, reg-loaded.
// EPI 0: relu -> x1b (cell rows, SLOT-packed). EPI 1: bf16 -> fv (SLOT-packed).
// ---------------------------------------------------------------------------
template <int KC, int EPI>
__global__ __launch_bounds__(256, 2) void convtap6_k(
    const unsigned short* __restrict__ A, const unsigned short* __restrict__ Bw,
    unsigned short* __restrict__ C) {
  __shared__ __align__(16) short Ah[256 * 72];
  const int tid = threadIdx.x;
  const int wave = tid >> 6, lane = tid & 63;
  const int wm = wave >> 1, wn = wave & 1;
  const int quad = lane >> 4, tq = lane & 15;
  const int img = blockIdx.x, n0 = blockIdx.y * 128;

  int pab[7];
  {
    const int dh = tq >> 3;
    int wq = wm * 8 + (tq & 7);          // w' in 0..15
    if (wq == 0) wq = 8;                 // dead col -> mirrored valid col
    else if (wq == 15) wq = 7;
#pragma unroll
    for (int mi = 0; mi < 7; ++mi) {
      int pr = (1 + 2 * mi + dh) * 16 + wq;   // 17..239
      pab[mi] = (pr - 17) * 144 + quad * 16;  // bytes
    }
  }
  const int gb = (n0 >> 4) + wn * 4;

  const char* Ab = (const char*)A;
  const char* AhB = (const char*)Ah;
  const int l16 = lane * 16;

  f32x4 acc[7][4];
#pragma unroll
  for (int mi = 0; mi < 7; ++mi)
#pragma unroll
    for (int ni = 0; ni < 4; ++ni) {
      f32x4 z = {0.f, 0.f, 0.f, 0.f};
      acc[mi][ni] = z;
    }

  auto stageA = [&](int kc) {
    size_t s0 = ((size_t)kc * RA + img * 256) * 144;
#pragma unroll
    for (int i = 0; i < 9; ++i) {
      int c = wave + i * 4;  // 36 chunks of 1024 B
      gload_lds16(Ab + s0 + (size_t)c * 1024 + l16, (char*)Ah + c * 1024);
    }
  };

  stageA(0);
  bf16x8 b0[4], b1[4];
  {  // h0 frags of (kc=0,t=0): overlaps A staging + barrier
    const size_t w0 = ((size_t)gb * 128 + lane) * 8;
#pragma unroll
    for (int ni = 0; ni < 4; ++ni)
      b0[ni] = *(const bf16x8*)&Bw[w0 + (size_t)ni * 1024];
  }
  __syncthreads();

#pragma unroll 1
  for (int kc = 0; kc < KC; ++kc) {
    const size_t bk = ((size_t)kc * 4096 + gb * 128 + lane) * 8;  // shorts
#pragma unroll
    for (int t = 0; t < 9; ++t) {
      const size_t tof = (size_t)t * KC * 32768;  // compile-time
#pragma unroll
      for (int ni = 0; ni < 4; ++ni)
        b1[ni] = *(const bf16x8*)&Bw[bk + tof + (size_t)ni * 1024 + 512];
      bf16x8 b0n[4];
      const bool last = (t == 8) && (kc == KC - 1);
      if (!last) {
        const size_t nbase =
            (t < 8) ? bk + (size_t)(t + 1) * KC * 32768 : bk + 32768;
#pragma unroll
        for (int ni = 0; ni < 4; ++ni)
          b0n[ni] = *(const bf16x8*)&Bw[nbase + (size_t)ni * 1024];
      }
      const int OFF = (17 + (t / 3 - 1) * 16 + (t % 3 - 1)) * 144;
      bf16x8 af0[7], af1[7];
#pragma unroll
      for (int mi = 0; mi < 7; ++mi)
        af0[mi] = *(const bf16x8*)(AhB + pab[mi] + OFF);
#pragma unroll
      for (int mi = 0; mi < 7; ++mi)
        af1[mi] = *(const bf16x8*)(AhB + pab[mi] + OFF + 64);
      __builtin_amdgcn_s_setprio(1);
#pragma unroll
      for (int mi = 0; mi < 7; ++mi)
#pragma unroll
        for (int ni = 0; ni < 4; ++ni)
          acc[mi][ni] = __builtin_amdgcn_mfma_f32_16x16x32_bf16(
              af0[mi], b0[ni], acc[mi][ni], 0, 0, 0);
#pragma unroll
      for (int mi = 0; mi < 7; ++mi)
#pragma unroll
        for (int ni = 0; ni < 4; ++ni)
          acc[mi][ni] = __builtin_amdgcn_mfma_f32_16x16x32_bf16(
              af1[mi], b1[ni], acc[mi][ni], 0, 0, 0);
      __builtin_amdgcn_s_setprio(0);
      if (!last) {
#pragma unroll
        for (int ni = 0; ni < 4; ++ni) b0[ni] = b0n[ni];  // SSA rename, free
      }
    }
    if (kc + 1 < KC) {  // kc-boundary restage (hidden by 3 co-resident blocks)
      __syncthreads();
      stageA(kc + 1);
      __syncthreads();
    }
  }

  // Packed epilogue: slot s = tq*4+ni -> one 8B store per (mi,r).
#pragma unroll
  for (int mi = 0; mi < 7; ++mi) {
#pragma unroll
    for (int r = 0; r < 4; ++r) {
      int idx = quad * 4 + r;            // M-row within tile, 0..15
      int wv = wm * 8 + (idx & 7);       // w' in 0..15
      if (wv == 0 || wv == 15) continue;  // dead column (halo)
      int hh = 1 + 2 * mi + (idx >> 3);  // h' in 1..14
      short4v s4;
#pragma unroll
      for (int ni = 0; ni < 4; ++ni) {
        float v = acc[mi][ni][r];
        s4[ni] = (short)f2bf(EPI == 0 ? fmaxf(v, 0.f) : v);
      }
      if (EPI == 0) {
        int cell = img * 256 + hh * 16 + wv;
        int slice = (n0 >> 6) + wn;
        size_t ob = ((size_t)slice * RA + cell) * 72 + tq * 4;
        *(short4v*)&C[ob] = s4;
      } else {
        int p = (hh - 1) * 14 + (wv - 1);
        size_t ob = (size_t)(img * 196 + p) * 512 + n0 + wn * 64 + tq * 4;
        *(short4v*)&C[ob] = s4;
      }
    }
  }
}

// ---------------------------------------------------------------------------
// gemm1_k: C[m,n] = sum_k A[m,k]*B[n,k]; 128x128 tile, 4 waves, BK=64,
// XOR-swizzled LDS, DOUBLE-BUFFERED staging (R11): stage(kc+1) issued before
// compute(kc); one barrier per K-step. Fixes the latency-serial K-loop of
// the tiny-grid fc1/fc2/xv dispatches (8 blocks; no TLP to hide staging).
// EPI: 0 relu->bf16, 2 f32, 3 f32 * rs[m] (row scale).
// ---------------------------------------------------------------------------
template <int K, int NLD, int EPI>
__global__ __launch_bounds__(256, 2) void gemm1_k(
    const unsigned short* __restrict__ A, const unsigned short* __restrict__ Bw,
    void* __restrict__ C, const float* __restrict__ rs) {
  __shared__ short As[2][128 * 64];
  __shared__ short Bs[2][128 * 64];
  const int tid = threadIdx.x;
  const int wave = tid >> 6, lane = tid & 63;
  const int m0 = blockIdx.x * 128, n0 = blockIdx.y * 128;
  const int rr8 = lane >> 3, seg = lane & 7, gseg = seg ^ rr8;
  const int wm = wave >> 1, wn = wave & 1;
  const int quad = lane >> 4, tq = lane & 15;

  size_t asrc[4], bsrc[4];
#pragma unroll
  for (int i8 = 0; i8 < 4; ++i8) {
    int rloc = wave * 32 + i8 * 8 + rr8;
    asrc[i8] = (size_t)(m0 + rloc) * K + gseg * 8;
    bsrc[i8] = (size_t)(n0 + rloc) * K + gseg * 8;
  }

  auto stage = [&](int kc2, int buf) {
    int kb = kc2 * 64;
#pragma unroll
    for (int i8 = 0; i8 < 4; ++i8) {
      gload_lds16(A + asrc[i8] + kb, &As[buf][(wave * 32 + i8 * 8) * 64]);
      gload_lds16(Bw + bsrc[i8] + kb, &Bs[buf][(wave * 32 + i8 * 8) * 64]);
    }
  };

  f32x4 acc[4][4];
#pragma unroll
  for (int mi = 0; mi < 4; ++mi)
#pragma unroll
    for (int ni = 0; ni < 4; ++ni) {
      f32x4 z = {0.f, 0.f, 0.f, 0.f};
      acc[mi][ni] = z;
    }

  const int NK = K / 64;
  stage(0, 0);
  __syncthreads();
#pragma unroll 1
  for (int kc2 = 0; kc2 < NK; ++kc2) {
    const int cur = kc2 & 1;
    if (kc2 + 1 < NK) stage(kc2 + 1, cur ^ 1);
#pragma unroll
    for (int h = 0; h < 2; ++h) {
      bf16x8 af[4], bfr[4];
#pragma unroll
      for (int mi = 0; mi < 4; ++mi) {
        int row = wm * 64 + mi * 16 + tq;
        af[mi] = *(const bf16x8*)&As[cur][row * 64 +
                                         ((((h << 2) | quad) ^ (row & 7)) << 3)];
      }
#pragma unroll
      for (int ni = 0; ni < 4; ++ni) {
        int row = wn * 64 + ni * 16 + tq;
        bfr[ni] = *(const bf16x8*)&Bs[cur][row * 64 +
                                           ((((h << 2) | quad) ^ (row & 7)) << 3)];
      }
#pragma unroll
      for (int mi = 0; mi < 4; ++mi)
#pragma unroll
        for (int ni = 0; ni < 4; ++ni)
          acc[mi][ni] = __builtin_amdgcn_mfma_f32_16x16x32_bf16(
              af[mi], bfr[ni], acc[mi][ni], 0, 0, 0);
    }
    __syncthreads();  // drains next-buf staging (issued ~1 compute-phase ago)
  }

#pragma unroll
  for (int mi = 0; mi < 4; ++mi) {
#pragma unroll
    for (int r = 0; r < 4; ++r) {
      int m = m0 + wm * 64 + mi * 16 + quad * 4 + r;
      float sc = (EPI == 3) ? rs[m] : 1.f;
      size_t obase = (size_t)m * NLD + n0 + wn * 64 + tq;
#pragma unroll
      for (int ni = 0; ni < 4; ++ni) {
        float v = acc[mi][ni][r];
        size_t idx = obase + ni * 16;
        if (EPI == 0)
          ((unsigned short*)C)[idx] = f2bf(fmaxf(v, 0.f));
        else if (EPI == 2)
          ((float*)C)[idx] = v;
        else
          ((float*)C)[idx] = v * sc;
      }
    }
  }
}

// Xm = (iv+eps).fa^T and Vm = indn.indn^T in one dispatch (blockIdx.z picks).
// Same R11 double-buffered staging (8 blocks -> latency-bound).
__global__ __launch_bounds__(256, 2) void gemm_xv_k(
    const unsigned short* __restrict__ ivpb, const unsigned short* __restrict__ fab,
    const unsigned short* __restrict__ indnb, float* __restrict__ Xm,
    float* __restrict__ Vm) {
  const unsigned short* A = blockIdx.z ? indnb : ivpb;
  const unsigned short* Bw = blockIdx.z ? indnb : fab;
  float* C = blockIdx.z ? Vm : Xm;
  __shared__ short As[2][128 * 64];
  __shared__ short Bs[2][128 * 64];
  const int tid = threadIdx.x;
  const int wave = tid >> 6, lane = tid & 63;
  const int m0 = blockIdx.x * 128, n0 = blockIdx.y * 128;
  const int rr8 = lane >> 3, seg = lane & 7, gseg = seg ^ rr8;
  const int wm = wave >> 1, wn = wave & 1;
  const int quad = lane >> 4, tq = lane & 15;
  size_t asrc[4], bsrc[4];
#pragma unroll
  for (int i8 = 0; i8 < 4; ++i8) {
    int rloc = wave * 32 + i8 * 8 + rr8;
    asrc[i8] = (size_t)(m0 + rloc) * 512 + gseg * 8;
    bsrc[i8] = (size_t)(n0 + rloc) * 512 + gseg * 8;
  }
  auto stage = [&](int kc2, int buf) {
    int kb = kc2 * 64;
#pragma unroll
    for (int i8 = 0; i8 < 4; ++i8) {
      gload_lds16(A + asrc[i8] + kb, &As[buf][(wave * 32 + i8 * 8) * 64]);
      gload_lds16(Bw + bsrc[i8] + kb, &Bs[buf][(wave * 32 + i8 * 8) * 64]);
    }
  };
  f32x4 acc[4][4];
#pragma unroll
  for (int mi = 0; mi < 4; ++mi)
#pragma unroll
    for (int ni = 0; ni < 4; ++ni) {
      f32x4 z = {0.f, 0.f, 0.f, 0.f};
      acc[mi][ni] = z;
    }
  stage(0, 0);
  __syncthreads();
#pragma unroll 1
  for (int kc2 = 0; kc2 < 8; ++kc2) {
    const int cur = kc2 & 1;
    if (kc2 + 1 < 8) stage(kc2 + 1, cur ^ 1);
#pragma unroll
    for (int h = 0; h < 2; ++h) {
      bf16x8 af[4], bfr[4];
#pragma unroll
      for (int mi = 0; mi < 4; ++mi) {
        int row = wm * 64 + mi * 16 + tq;
        af[mi] = *(const bf16x8*)&As[cur][row * 64 +
                                         ((((h << 2) | quad) ^ (row & 7)) << 3)];
      }
#pragma unroll
      for (int ni = 0; ni < 4; ++ni) {
        int row = wn * 64 + ni * 16 + tq;
        bfr[ni] = *(const bf16x8*)&Bs[cur][row * 64 +
                                           ((((h << 2) | quad) ^ (row & 7)) << 3)];
      }
#pragma unroll
      for (int mi = 0; mi < 4; ++mi)
#pragma unroll
        for (int ni = 0; ni < 4; ++ni)
          acc[mi][ni] = __builtin_amdgcn_mfma_f32_16x16x32_bf16(
              af[mi], bfr[ni], acc[mi][ni], 0, 0, 0);
    }
    __syncthreads();
  }
#pragma unroll
  for (int mi = 0; mi < 4; ++mi)
#pragma unroll
    for (int r = 0; r < 4; ++r) {
      int m = m0 + wm * 64 + mi * 16 + quad * 4 + r;
      size_t obase = (size_t)m * 256 + n0 + wn * 64 + tq;
#pragma unroll
      for (int ni = 0; ni < 4; ++ni) C[obase + ni * 16] = acc[mi][ni][r];
    }
}

// --------------------------- prep (fused) ----------------------------------
// ranges: ea/Wf1/Wf2 casts | wb1 build | wb2 build | x1b halo zeroing
// wb layout (fragment-packed): flat index j =
//   (((t*KC+kc)*32 + g)*2 + h)*512 + quad*128 + tq*8 + jj,  n = g*16+tq.
// wb1 (conv1, input=evb identity channels): cin = kc*64 + h*32 + quad*8 + jj
// wb2 (conv2, input=x1b SLOT-packed by conv1's epilogue):
//   cin = kc*64 + (jj&3)*16 + h*8 + quad*2 + (jj>>2).
__global__ void prep_all_k(const float* __restrict__ ea,
                           const float* __restrict__ Wf1,
                           const float* __restrict__ Wf2,
                           const float* __restrict__ Wc1,
                           const float* __restrict__ Wc2,
                           unsigned short* __restrict__ eab,
                           unsigned short* __restrict__ wf1b,
                           unsigned short* __restrict__ wf2b,
                           unsigned short* __restrict__ wb1,
                           unsigned short* __restrict__ wb2,
                           unsigned int* __restrict__ x1u) {
  int i = blockIdx.x * 256 + threadIdx.x;
  if (i < 524288) {
    eab[i] = f2bf(ea[i]);
  } else if (i < 1572864) {
    int j = i - 524288;
    wf1b[j] = f2bf(Wf1[j]);
  } else if (i < 1835008) {
    int j = i - 1572864;
    wf2b[j] = f2bf(Wf2[j]);
  } else if (i < 3604480) {
    int j = i - 1835008;  // wb1: 9*6*32768 fragment-packed <- Wc1[n][384][3][3]
    int t = j / (6 * 32768), r = j - t * (6 * 32768);
    int kc = r / 32768, r2 = r - kc * 32768;
    int g = r2 >> 10, h = (r2 >> 9) & 1, quad = (r2 >> 7) & 3;
    int tq = (r2 >> 3) & 15, jj = r2 & 7;
    int n = g * 16 + tq, cin = kc * 64 + h * 32 + quad * 8 + jj;
    wb1[j] = f2bf(Wc1[(n * 384 + cin) * 9 + t]);
  } else if (i < 5963776) {
    int j = i - 3604480;  // wb2: 9*8*32768 fragment-packed <- Wc2[n][512][3][3]
    int t = j / (8 * 32768), r = j - t * (8 * 32768);
    int kc = r / 32768, r2 = r - kc * 32768;
    int g = r2 >> 10, h = (r2 >> 9) & 1, quad = (r2 >> 7) & 3;
    int tq = (r2 >> 3) & 15, jj = r2 & 7;
    int n = g * 16 + tq;
    int cin = kc * 64 + (jj & 3) * 16 + h * 8 + quad * 2 + (jj >> 2);
    wb2[j] = f2bf(Wc2[(n * 512 + cin) * 9 + t]);
  } else {
    int j = i - 5963776;  // 15360 halo rows x 8 slices x 32 uints
    int hr = j >> 8, u = j & 255;
    int slice = u >> 5, uu = u & 31;
    int b = hr / 60, c = hr - b * 60;
    int cell;
    if (c < 16) cell = c;
    else if (c < 32) cell = 240 + (c - 16);
    else if (c < 46) cell = (c - 31) * 16;
    else cell = (c - 45) * 16 + 15;
    x1u[((size_t)slice * RA + b * 256 + cell) * 36 + uu] = 0u;
  }
}

// ev (256,384,14,14) fp32 -> evb [kc6][RA][72] bf16 (halo cells zero)
__global__ __launch_bounds__(256) void evpad_k(const float* __restrict__ ev,
                                               unsigned short* __restrict__ out) {
  int b = blockIdx.x, ct = blockIdx.y;  // channel tile: c0 = ct*64
  __shared__ float tile[64][197];
  int tid = threadIdx.x;
  const float* src = ev + ((size_t)b * 384 + ct * 64) * 196;
#pragma unroll 1
  for (int it = 0; it < 49; ++it) {
    int idx = it * 256 + tid;
    int c = idx / 196, p = idx - c * 196;
    tile[c][p] = src[idx];
  }
  __syncthreads();
  unsigned short* dst = out + ((size_t)ct * RA + b * 256) * 72;
#pragma unroll 1
  for (int it = 0; it < 64; ++it) {
    int idx = it * 256 + tid;
    int cell = idx >> 6, c = idx & 63;
    int h = (cell >> 4) - 1, w = (cell & 15) - 1;
    float v = ((unsigned)h < 14u && (unsigned)w < 14u) ? tile[c][h * 14 + w]
                                                       : 0.f;
    dst[(size_t)cell * 72 + c] = f2bf(v);
  }
}

// --------------------------- pooling / norms (fused, R11) ------------------
// grid 512: b<256 -> pool role (masked mean pool + rn + ind normalization);
// b>=256 -> fanorm role (fa cast in SLOT order + Qj).
__global__ __launch_bounds__(512) void poolfa_k(
    const unsigned short* __restrict__ fv, const int* __restrict__ masks,
    const float* __restrict__ fa, unsigned short* __restrict__ indnb,
    unsigned short* __restrict__ ivpb, unsigned short* __restrict__ fab,
    float* __restrict__ Pi, float* __restrict__ Qj, float* __restrict__ rn) {
  int bid = blockIdx.x;
  int tid = threadIdx.x;
  if (bid >= 256) {  // fanorm: slot s -> channel (s&3)*16 + (s>>2)
    int b = bid - 256;
    int s64 = tid & 63;
    int chan = (tid & ~63) | ((s64 & 3) * 16 + (s64 >> 2));
    float v = fa[b * 512 + chan];
    fab[b * 512 + tid] = f2bf(v);
    float q = blockSum<8>(v * v);  // permutation-invariant
    if (tid == 0) Qj[b] = q;
    return;
  }
  int b = bid;
  int w = tid >> 6, lane = tid & 63;
  __shared__ float red[8][512];
  __shared__ float msh[8];
  float acc[8] = {0.f, 0.f, 0.f, 0.f, 0.f, 0.f, 0.f, 0.f};
  float msum = 0.f;
  for (int p = w; p < 196; p += 8) {
    float m = (float)masks[b * 196 + p];
    msum += m;
    uint4 d = *(const uint4*)(fv + (size_t)(b * 196 + p) * 512 + lane * 8);
    const unsigned short* hp = (const unsigned short*)&d;
    float ss = 0.f;
#pragma unroll
    for (int k = 0; k < 8; ++k) {
      float x = bf2f(hp[k]);
      ss += x * x;
      acc[k] += m * x;
    }
    ss = waveSum(ss);
    if (lane == 0) rn[b * 196 + p] = 1.f / fmaxf(sqrtf(ss), 1e-12f);
  }
#pragma unroll
  for (int k = 0; k < 8; ++k) red[w][lane * 8 + k] = acc[k];
  if (lane == 0) msh[w] = msum;
  __syncthreads();
  float s = 0.f, mtot = 0.f;
#pragma unroll
  for (int ww = 0; ww < 8; ++ww) {
    s += red[ww][tid];
    mtot += msh[ww];
  }
  float v = s / mtot;  // indv[b, slot tid]
  float ss2 = blockSum<8>(v * v);
  float sc = 1.f / fmaxf(sqrtf(ss2), 1e-12f);
  indnb[b * 512 + tid] = f2bf(v * sc);
  float ve = v + 1e-6f;
  ivpb[b * 512 + tid] = f2bf(ve);
  float p2 = blockSum<8>(ve * ve);
  if (tid == 0) Pi[b] = p2;
}

// ------------------------------ SP / SN ------------------------------------

__device__ __forceinline__ float radix_kth(unsigned k0, unsigned k1, unsigned k2,
                                           unsigned k3, int k) {
  unsigned prefix = 0;
  int kk = k;
#pragma unroll 1
  for (int bit = 31; bit >= 14; --bit) {  // 18 steps; thr err ~2^-9 rel, ok
    unsigned thi = (prefix >> bit) | 1u;
    int c = __popcll(__ballot((k0 >> bit) == thi)) +
            __popcll(__ballot((k1 >> bit) == thi)) +
            __popcll(__ballot((k2 >> bit) == thi)) +
            __popcll(__ballot((k3 >> bit) == thi));
    if (kk <= c)
      prefix |= (1u << bit);
    else
      kk -= c;
  }
  unsigned u = (prefix & 0x80000000u) ? (prefix ^ 0x80000000u) : ~prefix;
  return __uint_as_float(u);
}
__device__ __forceinline__ unsigned sortkey(float x) {
  unsigned u = __float_as_uint(x);
  return u ^ (((int)u >> 31) | 0x80000000u);
}

__global__ __launch_bounds__(256) void spsn_k(const float* __restrict__ Sij,
                                              float* __restrict__ SP,
                                              float* __restrict__ SN) {
  int i = blockIdx.x, jg = blockIdx.y;
  int tid = threadIdx.x, wave = tid >> 6, lane = tid & 63;
  __shared__ float tile[196 * 65];
#pragma unroll 1
  for (int it = 0; it < 49; ++it) {
    int lin = it * 256 + tid;
    int p = lin >> 6, j = lin & 63;
    tile[p * 65 + j] = Sij[(size_t)(i * 196 + p) * 256 + jg * 64 + j];
  }
  __syncthreads();
#pragma unroll 1
  for (int jj = 0; jj < 16; ++jj) {
    int j = jj * 4 + wave;
    float v0 = tile[lane * 65 + j];
    float v1 = tile[(lane + 64) * 65 + j];
    float v2 = tile[(lane + 128) * 65 + j];
    bool val3 = lane < 4;
    float v3 = val3 ? tile[(lane + 192) * 65 + j] : 0.f;
    unsigned k0 = sortkey(v0), k1 = sortkey(v1), k2 = sortkey(v2);
    unsigned k3 = val3 ? sortkey(v3) : 0u;
    float thrP = radix_kth(k0, k1, k2, k3, 19);
    float thrN = radix_kth(k0, k1, k2, k3, 99);
    float spn = 0.f, spd = 0.f, snn = 0.f, snd = 0.f;
    const float invTS = 1.f / 0.03f;
#pragma unroll
    for (int q = 0; q < 4; ++q) {
      float v = (q == 0) ? v0 : (q == 1) ? v1 : (q == 2) ? v2 : v3;
      bool ok = (q < 3) || val3;
      if (ok) {
        float mp = 1.f / (1.f + __expf((thrP - v) * invTS));
        float mn = 1.f / (1.f + __expf((v - thrN) * invTS));
        spn += v * mp;
        spd += mp;
        snn += v * mn;
        snd += mn;
      }
    }
    spn = waveSum(spn); spd = waveSum(spd);
    snn = waveSum(snn); snd = waveSum(snd);
    if (lane == 0) {
      SP[i * 256 + jg * 64 + j] = spn / spd;
      SN[i * 256 + jg * 64 + j] = snn / snd;
    }
  }
}

// fused loss12 + distcomb (R11): grid 768.
// r<512: loss12 (row/col LSE of [SP|SN]/TC). r>=512: distcomb row i=r-512.
__global__ __launch_bounds__(256) void lossA_k(
    const float* __restrict__ SP, const float* __restrict__ SN,
    const float* __restrict__ Pi, const float* __restrict__ Qj,
    const float* __restrict__ X, const float* __restrict__ V,
    float* __restrict__ val, float* __restrict__ out) {
  int r = blockIdx.x;
  int tid = threadIdx.x;
  if (r < 512) {
    int i = r & 255;
    bool col = r >= 256;
    const float invTC = 1.f / 0.07f;
    float a = (col ? SP[tid * 256 + i] : SP[i * 256 + tid]) * invTC;
    float b = (col ? SN[tid * 256 + i] : SN[i * 256 + tid]) * invTC;
    float mx = blockMax<4>(fmaxf(a, b));
    float se = blockSum<4>(__expf(a - mx) + __expf(b - mx));
    float lse = mx + __logf(se);
    if (tid == 0) {
      float diag = SP[i * 256 + i] * invTC;
      atomicAdd(out, -(diag - lse) * (1.f / 512.f));
    }
  } else {
    int i = r - 512, j = tid;
    float d = Pi[i] - 2.f * X[i * 256 + j] + Qj[j];
    float w = (i == j) ? 1.f : -V[i * 256 + j];
    float x = d * w;
    val[i * 256 + j] = x;
    __shared__ float diag_sh;
    if (j == i) diag_sh = x;
    float tot = blockSum<4>(x);
    if (j == 0) {
      float rs = diag_sh - (tot - diag_sh) * (1.f / 255.f);
      atomicAdd(out + 1, fmaxf(rs + 0.6f, 0.f) * (1.f / 512.f));
    }
  }
}

__global__ __launch_bounds__(256) void loss4_k(const float* __restrict__ val,
                                               float* __restrict__ out) {
  int j = blockIdx.x, i = threadIdx.x;
  float x = val[i * 256 + j];
  __shared__ float diag_sh;
  if (i == j) diag_sh = x;
  float tot = blockSum<4>(x);
  if (i == 0) {
    float cs = diag_sh - (tot - diag_sh) * (1.f / 255.f);
    atomicAdd(out + 1, fmaxf(cs + 0.6f, 0.f) * (1.f / 512.f));
  }
}

// ---------------------------------------------------------------------------

extern "C" void kernel_launch(void* const* d_in, const int* in_sizes, int n_in,
                              void* d_out, int out_size, void* d_ws,
                              size_t ws_size, hipStream_t stream) {
  (void)in_sizes; (void)n_in; (void)out_size; (void)ws_size;
  const float* ev = (const float*)d_in[0];
  const float* ea = (const float*)d_in[1];
  const int* msk = (const int*)d_in[2];
  const float* Wf1 = (const float*)d_in[3];
  const float* Wf2 = (const float*)d_in[4];
  const float* Wc1 = (const float*)d_in[5];
  const float* Wc2 = (const float*)d_in[6];
  float* out = (float*)d_out;
  char* ws = (char*)d_ws;

  size_t off = 0;
  auto alloc = [&](size_t bytes) {
    void* p = ws + off;
    off = (off + bytes + 255) & ~(size_t)255;
    return p;
  };
  // Region 1: max(evb 6*RA*144 = 56.6 MB ; fv 50176*512*2 = 51.4 MB)
  unsigned short* evb = (unsigned short*)alloc((size_t)6 * RA * 144);
  unsigned short* fv = evb;  // reused after conv2
  // Region 2: max(x1b 8*RA*144 = 75.5 MB ; Sij 50176*256*4 = 51.4 MB)
  unsigned short* x1b = (unsigned short*)alloc((size_t)8 * RA * 144);
  float* Sij = (float*)x1b;  // reused after conv2
  unsigned short* wb1 = (unsigned short*)alloc((size_t)9 * 6 * 32768 * 2);
  unsigned short* wb2 = (unsigned short*)alloc((size_t)9 * 8 * 32768 * 2);
  unsigned short* eab = (unsigned short*)alloc((size_t)256 * 2048 * 2);
  unsigned short* wf1b = (unsigned short*)alloc((size_t)512 * 2048 * 2);
  unsigned short* wf2b = (unsigned short*)alloc((size_t)512 * 512 * 2);
  unsigned short* hb = (unsigned short*)alloc((size_t)256 * 512 * 2);
  float* fa = (float*)alloc((size_t)256 * 512 * 4);
  unsigned short* indnb = (unsigned short*)alloc((size_t)256 * 512 * 2);
  unsigned short* ivpb = (unsigned short*)alloc((size_t)256 * 512 * 2);
  unsigned short* fab = (unsigned short*)alloc((size_t)256 * 512 * 2);
  float* Pi = (float*)alloc(256 * 4);
  float* Qj = (float*)alloc(256 * 4);
  float* Xm = (float*)alloc((size_t)256 * 256 * 4);
  float* Vm = (float*)alloc((size_t)256 * 256 * 4);
  float* rn = (float*)alloc((size_t)50176 * 4);
  float* SP = (float*)alloc((size_t)256 * 256 * 4);
  float* SN = (float*)alloc((size_t)256 * 256 * 4);
  float* val = (float*)alloc((size_t)256 * 256 * 4);

  hipMemsetAsync(out, 0, 2 * sizeof(float), stream);

  prep_all_k<<<38656, 256, 0, stream>>>(ea, Wf1, Wf2, Wc1, Wc2, eab, wf1b,
                                        wf2b, wb1, wb2, (unsigned int*)x1b);
  evpad_k<<<dim3(256, 6), 256, 0, stream>>>(ev, evb);

  // conv1: relu, cell rows k-major (one image per block-x, N=512, K=9*384)
  convtap6_k<6, 0><<<dim3(256, 4), 256, 0, stream>>>(evb, wb1, x1b);
  // fc1 / fc2 (dbuf staging)
  gemm1_k<2048, 512, 0><<<dim3(2, 4), 256, 0, stream>>>(eab, wf1b, hb, nullptr);
  gemm1_k<512, 512, 2><<<dim3(2, 4), 256, 0, stream>>>(hb, wf2b, fa, nullptr);
  // conv2: compact bf16 out (one image per block-x, N=512, K=9*512)
  convtap6_k<8, 1><<<dim3(256, 4), 256, 0, stream>>>(x1b, wb2, fv);

  poolfa_k<<<512, 512, 0, stream>>>(fv, msk, fa, indnb, ivpb, fab, Pi, Qj, rn);

  // Sij[(i,p), j] = rn[i,p] * <fv[i,p,:], indn[j,:]>  (M=50176, N=256, K=512)
  gemm1_k<512, 256, 3><<<dim3(392, 2), 256, 0, stream>>>(fv, indnb, Sij, rn);
  gemm_xv_k<<<dim3(2, 2, 2), 256, 0, stream>>>(ivpb, fab, indnb, Xm, Vm);

  spsn_k<<<dim3(256, 4), 256, 0, stream>>>(Sij, SP, SN);
  lossA_k<<<768, 256, 0, stream>>>(SP, SN, Pi, Qj, Xm, Vm, val, out);
  loss4_k<<<256, 256, 0, stream>>>(val, out);
}